// Round 2
// baseline (509.796 us; speedup 1.0000x reference)
//
#include <hip/hip_runtime.h>
#include <hip/hip_bf16.h>
#include <math.h>

// ---------------- problem constants ----------------
#define B_    128
#define N_    196
#define E_    768
#define K_    8
#define D_    128
#define BNR   (B_*N_)        // 25088 rows
#define ITERS 5

// ws layout (in floats)
#define OFF_STATS 0            // 25088*2
#define OFF_WQT   50176        // 128*128
#define OFF_WIHT  66560        // 128*384
#define OFF_WHHT  115712       // 128*384
#define OFF_W1T   164864       // 128*128
#define OFF_W2T   181248       // 128*128
#define OFF_DW1T  197632       // 128*256
#define OFF_DW2T  230400       // 256*768
#define OFF_DW3T  427008       // 768*768
#define OFF_KP    1016832      // 25088*128
#define OFF_VP    4228096      // 25088*128
#define OFF_SF    7439360      // 1024*768
#define OFF_PART  8225792      // 512

__device__ __forceinline__ float wave_red_sum64(float v) {
    #pragma unroll
    for (int o = 32; o > 0; o >>= 1) v += __shfl_xor(v, o);
    return v;
}

// ---------------- generic 32x32 tiled transpose (dims multiple of 32) ----------------
// src: [R][C] row-major, dst: [C][R] row-major
__global__ __launch_bounds__(256) void tK(const float* __restrict__ src,
                                          float* __restrict__ dst, int R, int C) {
    __shared__ float tile[32][33];
    int bx = blockIdx.x * 32;   // c
    int by = blockIdx.y * 32;   // r
    int tx = threadIdx.x, ty = threadIdx.y;  // (32,8)
    #pragma unroll
    for (int i = 0; i < 32; i += 8) {
        tile[ty + i][tx] = src[(size_t)(by + ty + i) * C + (bx + tx)];
    }
    __syncthreads();
    #pragma unroll
    for (int i = 0; i < 32; i += 8) {
        dst[(size_t)(bx + ty + i) * R + (by + tx)] = tile[tx][ty + i];
    }
}

// ---------------- K1: per-row mean/rstd of features ----------------
__global__ __launch_bounds__(256) void ln_stats_k(const float* __restrict__ f,
                                                  float* __restrict__ stats) {
    int gtid = blockIdx.x * 256 + threadIdx.x;
    int wid = gtid >> 6;
    int lane = gtid & 63;
    if (wid >= BNR) return;
    const float* row = f + (size_t)wid * E_;
    float s = 0.f, s2 = 0.f;
    for (int i = lane * 4; i < E_; i += 256) {
        float4 v = *(const float4*)(row + i);
        s  += v.x + v.y + v.z + v.w;
        s2 += v.x*v.x + v.y*v.y + v.z*v.z + v.w*v.w;
    }
    s  = wave_red_sum64(s);
    s2 = wave_red_sum64(s2);
    if (lane == 0) {
        float m = s * (1.f / E_);
        float var = s2 * (1.f / E_) - m * m;
        stats[wid*2]   = m;
        stats[wid*2+1] = rsqrtf(var + 1e-5f);
    }
}

// ---------------- K2: fused k_proj/v_proj SGEMM with on-the-fly LayerNorm ----------------
// C[25088, 0:128]=LN(feats)@Wk.T * scale ; C[25088,128:256]=LN(feats)@Wv.T
__global__ __launch_bounds__(256) void proj_k(const float* __restrict__ feats,
                                              const float* __restrict__ stats,
                                              const float* __restrict__ g,
                                              const float* __restrict__ bvec,
                                              const float* __restrict__ Wk,
                                              const float* __restrict__ Wv,
                                              float* __restrict__ kp,
                                              float* __restrict__ vp) {
    __shared__ float As[16][68];
    __shared__ float Bs[16][260];
    const float kscale = 0.08838834764831845f;  // 128^-0.5
    int m0 = blockIdx.x * 64;
    int t = threadIdx.x;
    int tx = t & 31, ty = t >> 5;
    int arow = t >> 2, aq = t & 3;
    float acc[8][8];
    #pragma unroll
    for (int i = 0; i < 8; ++i)
        #pragma unroll
        for (int j = 0; j < 8; ++j) acc[i][j] = 0.f;

    float mu = stats[(m0 + arow) * 2];
    float rs = stats[(m0 + arow) * 2 + 1];

    for (int ks = 0; ks < E_; ks += 16) {
        // A tile: 64 rows x 16 k (LN applied), stored transposed As[kk][row]
        {
            float4 x4 = *(const float4*)(feats + (size_t)(m0 + arow) * E_ + ks + aq * 4);
            float4 g4 = *(const float4*)(g + ks + aq * 4);
            float4 b4 = *(const float4*)(bvec + ks + aq * 4);
            As[aq*4+0][arow] = (x4.x - mu) * rs * g4.x + b4.x;
            As[aq*4+1][arow] = (x4.y - mu) * rs * g4.y + b4.y;
            As[aq*4+2][arow] = (x4.z - mu) * rs * g4.z + b4.z;
            As[aq*4+3][arow] = (x4.w - mu) * rs * g4.w + b4.w;
        }
        // B tile: 256 n x 16 k, stored transposed Bs[kk][n]; scale folded for k-cols
        #pragma unroll
        for (int p = 0; p < 4; ++p) {
            int n = p * 64 + (t >> 2);
            const float* Wp; float sc;
            if (n < 128) { Wp = Wk + (size_t)n * E_;        sc = kscale; }
            else         { Wp = Wv + (size_t)(n - 128) * E_; sc = 1.f;   }
            float4 w4 = *(const float4*)(Wp + ks + aq * 4);
            Bs[aq*4+0][n] = w4.x * sc;
            Bs[aq*4+1][n] = w4.y * sc;
            Bs[aq*4+2][n] = w4.z * sc;
            Bs[aq*4+3][n] = w4.w * sc;
        }
        __syncthreads();
        #pragma unroll
        for (int kk = 0; kk < 16; ++kk) {
            float a[8];
            float4 a0 = *(const float4*)&As[kk][ty * 8];
            float4 a1 = *(const float4*)&As[kk][ty * 8 + 4];
            a[0]=a0.x; a[1]=a0.y; a[2]=a0.z; a[3]=a0.w;
            a[4]=a1.x; a[5]=a1.y; a[6]=a1.z; a[7]=a1.w;
            float4 bb0 = *(const float4*)&Bs[kk][tx * 4];
            float4 bb1 = *(const float4*)&Bs[kk][128 + tx * 4];
            #pragma unroll
            for (int i = 0; i < 8; ++i) {
                acc[i][0] += a[i] * bb0.x; acc[i][1] += a[i] * bb0.y;
                acc[i][2] += a[i] * bb0.z; acc[i][3] += a[i] * bb0.w;
                acc[i][4] += a[i] * bb1.x; acc[i][5] += a[i] * bb1.y;
                acc[i][6] += a[i] * bb1.z; acc[i][7] += a[i] * bb1.w;
            }
        }
        __syncthreads();
    }
    #pragma unroll
    for (int i = 0; i < 8; ++i) {
        int row = m0 + ty * 8 + i;
        *(float4*)(kp + (size_t)row * D_ + tx * 4) =
            make_float4(acc[i][0], acc[i][1], acc[i][2], acc[i][3]);
        *(float4*)(vp + (size_t)row * D_ + tx * 4) =
            make_float4(acc[i][4], acc[i][5], acc[i][6], acc[i][7]);
    }
}

// ---- helpers for the iteration kernel ----
// LN over 8 rows of 128 (one wave per row); caller syncs around it.
__device__ __forceinline__ void ln_8x128(const float (*src)[128], float (*dst)[128],
                                         const float* __restrict__ g,
                                         const float* __restrict__ bvec, int t) {
    int k = t >> 6, lane = t & 63;
    float x0 = src[k][lane], x1 = src[k][lane + 64];
    float s  = wave_red_sum64(x0 + x1);
    float s2 = wave_red_sum64(x0 * x0 + x1 * x1);
    float m = s * (1.f / 128.f);
    float var = s2 * (1.f / 128.f) - m * m;
    float rs = rsqrtf(var + 1e-5f);
    dst[k][lane]      = (x0 - m) * rs * g[lane]      + bvec[lane];
    dst[k][lane + 64] = (x1 - m) * rs * g[lane + 64] + bvec[lane + 64];
}

// out[k][dout] partials for in[8][128] @ WT[128][128]; 4-way split over j.
__device__ __forceinline__ void mv128(const float (*in)[128], const float* __restrict__ WT,
                                      float (*part)[8][128], int t) {
    int dout = t & 127, jc = t >> 7;
    float a[8] = {0.f,0.f,0.f,0.f,0.f,0.f,0.f,0.f};
    int j0 = jc * 32;
    #pragma unroll 4
    for (int j = j0; j < j0 + 32; ++j) {
        float wv = WT[j * 128 + dout];
        #pragma unroll
        for (int k = 0; k < 8; ++k) a[k] += in[k][j] * wv;
    }
    #pragma unroll
    for (int k = 0; k < 8; ++k) part[jc][k][dout] = a[k];
}

// ---------------- K3: persistent per-batch slot-attention iterations ----------------
__global__ __launch_bounds__(512) void slot_iter_k(
    const float* __restrict__ noise,
    const float* __restrict__ lsg, const float* __restrict__ lsb,
    const float* __restrict__ log_, const float* __restrict__ lob,
    const float* __restrict__ mup, const float* __restrict__ lsig,
    const float* __restrict__ WqT, const float* __restrict__ WihT,
    const float* __restrict__ WhhT,
    const float* __restrict__ bih, const float* __restrict__ bhh,
    const float* __restrict__ W1T, const float* __restrict__ mb1,
    const float* __restrict__ W2T, const float* __restrict__ mb2,
    const float* __restrict__ kp, const float* __restrict__ vp,
    float* __restrict__ out_slots, float* __restrict__ out_attn) {

    __shared__ float slots[8][128];
    __shared__ float sln[8][128];
    __shared__ float qb[8][128];
    __shared__ float upd[8][128];
    __shared__ float attn[196][9];
    __shared__ float gi[8][384];
    __shared__ float gh[8][384];
    __shared__ float part[4][8][128];
    __shared__ float colsum[8];

    int b = blockIdx.x, t = threadIdx.x;
    int lane = t & 63, w = t >> 6;
    const float* kpb = kp + (size_t)b * N_ * D_;
    const float* vpb = vp + (size_t)b * N_ * D_;

    // init slots = noise * exp(log_sigma) + mu
    for (int idx = t; idx < 1024; idx += 512) {
        int d = idx & 127;
        slots[idx >> 7][d] = noise[(size_t)b * 1024 + idx] * expf(lsig[d]) + mup[d];
    }

    for (int it = 0; it < ITERS; ++it) {
        __syncthreads();
        // (a) s_ln = LN_slot(slots)
        ln_8x128(slots, sln, lsg, lsb, t);
        __syncthreads();
        // (b) q = s_ln @ Wq.T
        mv128(sln, WqT, part, t);
        __syncthreads();
        for (int idx = t; idx < 1024; idx += 512) {
            int k = idx >> 7, d = idx & 127;
            qb[k][d] = part[0][k][d] + part[1][k][d] + part[2][k][d] + part[3][k][d];
        }
        __syncthreads();
        // (c) logits + softmax over slots
        {
            int sub = lane >> 3, dgi = lane & 7, dg = dgi * 16;
            bool lastit = (it == ITERS - 1);
            #pragma unroll
            for (int p = 0; p < 4; ++p) {
                int n = p * 64 + w * 8 + sub;
                if (n < N_) {
                    float kv[16];
                    *(float4*)&kv[0]  = *(const float4*)(kpb + (size_t)n * D_ + dg);
                    *(float4*)&kv[4]  = *(const float4*)(kpb + (size_t)n * D_ + dg + 4);
                    *(float4*)&kv[8]  = *(const float4*)(kpb + (size_t)n * D_ + dg + 8);
                    *(float4*)&kv[12] = *(const float4*)(kpb + (size_t)n * D_ + dg + 12);
                    float l8[8];
                    #pragma unroll
                    for (int k = 0; k < 8; ++k) {
                        float acc = 0.f;
                        #pragma unroll
                        for (int i = 0; i < 16; ++i) acc += kv[i] * qb[k][dg + i];
                        l8[k] = acc;
                    }
                    #pragma unroll
                    for (int o = 1; o < 8; o <<= 1) {
                        #pragma unroll
                        for (int k = 0; k < 8; ++k) l8[k] += __shfl_xor(l8[k], o);
                    }
                    float m = l8[0];
                    #pragma unroll
                    for (int k = 1; k < 8; ++k) m = fmaxf(m, l8[k]);
                    float e[8], s = 0.f;
                    #pragma unroll
                    for (int k = 0; k < 8; ++k) { e[k] = expf(l8[k] - m); s += e[k]; }
                    float inv = 1.f / s;
                    if (dgi == 0) {
                        #pragma unroll
                        for (int k = 0; k < 8; ++k) attn[n][k] = e[k] * inv;
                        if (lastit) {
                            *(float4*)(out_attn + ((size_t)b * N_ + n) * 8) =
                                make_float4(e[0]*inv, e[1]*inv, e[2]*inv, e[3]*inv);
                            *(float4*)(out_attn + ((size_t)b * N_ + n) * 8 + 4) =
                                make_float4(e[4]*inv, e[5]*inv, e[6]*inv, e[7]*inv);
                        }
                    }
                }
            }
        }
        __syncthreads();
        // (d) column sums over tokens, then normalize
        {
            float s = 0.f;
            for (int n = lane; n < N_; n += 64) s += attn[n][w] + 1e-8f;
            s = wave_red_sum64(s);
            if (lane == 0) colsum[w] = s;
        }
        __syncthreads();
        for (int idx = t; idx < N_ * 8; idx += 512) {
            int n = idx >> 3, k = idx & 7;
            attn[n][k] = (attn[n][k] + 1e-8f) / colsum[k];
        }
        __syncthreads();
        // (e) updates = attn.T @ v
        {
            int dout = t & 127, nc = t >> 7;
            float a[8] = {0.f,0.f,0.f,0.f,0.f,0.f,0.f,0.f};
            int n0 = nc * 49;
            for (int n = n0; n < n0 + 49; ++n) {
                float v = vpb[(size_t)n * D_ + dout];
                #pragma unroll
                for (int k = 0; k < 8; ++k) a[k] += attn[n][k] * v;
            }
            #pragma unroll
            for (int k = 0; k < 8; ++k) part[nc][k][dout] = a[k];
        }
        __syncthreads();
        for (int idx = t; idx < 1024; idx += 512) {
            int k = idx >> 7, d = idx & 127;
            upd[k][d] = part[0][k][d] + part[1][k][d] + part[2][k][d] + part[3][k][d];
        }
        __syncthreads();
        // (f) GRU matvecs: gi = upd@W_ih.T + b_ih ; gh = slots@W_hh.T + b_hh
        if (t < 384) {
            float gia[8] = {0.f,0.f,0.f,0.f,0.f,0.f,0.f,0.f};
            float gha[8] = {0.f,0.f,0.f,0.f,0.f,0.f,0.f,0.f};
            #pragma unroll 4
            for (int j = 0; j < 128; ++j) {
                float wi = WihT[j * 384 + t];
                float wh = WhhT[j * 384 + t];
                #pragma unroll
                for (int k = 0; k < 8; ++k) {
                    gia[k] += upd[k][j] * wi;
                    gha[k] += slots[k][j] * wh;
                }
            }
            float bi = bih[t], bh = bhh[t];
            #pragma unroll
            for (int k = 0; k < 8; ++k) {
                gi[k][t] = gia[k] + bi;
                gh[k][t] = gha[k] + bh;
            }
        }
        __syncthreads();
        // (g) gates, in-place slot update
        for (int idx = t; idx < 1024; idx += 512) {
            int k = idx >> 7, d = idx & 127;
            float ir = gi[k][d], iz = gi[k][128 + d], inn = gi[k][256 + d];
            float hr = gh[k][d], hz = gh[k][128 + d], hn = gh[k][256 + d];
            float r = 1.f / (1.f + expf(-(ir + hr)));
            float z = 1.f / (1.f + expf(-(iz + hz)));
            float nn = tanhf(inn + r * hn);
            float h = slots[k][d];
            slots[k][d] = (1.f - z) * nn + z * h;
        }
        __syncthreads();
        // (h) MLP residual: slots += relu(LN_out(slots)@W1.T+b1)@W2.T + b2
        ln_8x128(slots, sln, log_, lob, t);
        __syncthreads();
        mv128(sln, W1T, part, t);
        __syncthreads();
        for (int idx = t; idx < 1024; idx += 512) {
            int k = idx >> 7, d = idx & 127;
            float v = part[0][k][d] + part[1][k][d] + part[2][k][d] + part[3][k][d] + mb1[d];
            qb[k][d] = fmaxf(v, 0.f);
        }
        __syncthreads();
        mv128(qb, W2T, part, t);
        __syncthreads();
        for (int idx = t; idx < 1024; idx += 512) {
            int k = idx >> 7, d = idx & 127;
            slots[k][d] += part[0][k][d] + part[1][k][d] + part[2][k][d] + part[3][k][d] + mb2[d];
        }
    }
    __syncthreads();
    for (int idx = t; idx < 1024; idx += 512)
        out_slots[(size_t)b * 1024 + idx] = slots[idx >> 7][idx & 127];
}

// ---------------- K4: decoder MLP per batch (grid.y splits final 768 cols) ----------------
__global__ __launch_bounds__(512) void decoder_k(
    const float* __restrict__ ldg_, const float* __restrict__ ldb,
    const float* __restrict__ dW1T, const float* __restrict__ db1,
    const float* __restrict__ dW2T, const float* __restrict__ db2,
    const float* __restrict__ dW3T, const float* __restrict__ db3,
    const float* __restrict__ slots_in, float* __restrict__ sf) {

    __shared__ float s[8][128];
    __shared__ float h1[8][256];
    __shared__ float h2[8][768];
    __shared__ float part[2][8][256];
    int b = blockIdx.x, half = blockIdx.y, t = threadIdx.x;
    int lane = t & 63, w = t >> 6;

    // LN_dec(slots)
    {
        float x0 = slots_in[(size_t)b * 1024 + w * 128 + lane];
        float x1 = slots_in[(size_t)b * 1024 + w * 128 + lane + 64];
        float su  = wave_red_sum64(x0 + x1);
        float su2 = wave_red_sum64(x0 * x0 + x1 * x1);
        float m = su * (1.f / 128.f);
        float var = su2 * (1.f / 128.f) - m * m;
        float rs = rsqrtf(var + 1e-5f);
        s[w][lane]      = (x0 - m) * rs * ldg_[lane]      + ldb[lane];
        s[w][lane + 64] = (x1 - m) * rs * ldg_[lane + 64] + ldb[lane + 64];
    }
    __syncthreads();
    // h1 = relu(s @ dW1.T + b1): 256 douts, j split 2x64
    {
        int dout = t & 255, jc = t >> 8;
        float a[8] = {0.f,0.f,0.f,0.f,0.f,0.f,0.f,0.f};
        int j0 = jc * 64;
        #pragma unroll 4
        for (int j = j0; j < j0 + 64; ++j) {
            float wv = dW1T[j * 256 + dout];
            #pragma unroll
            for (int k = 0; k < 8; ++k) a[k] += s[k][j] * wv;
        }
        #pragma unroll
        for (int k = 0; k < 8; ++k) part[jc][k][dout] = a[k];
    }
    __syncthreads();
    for (int idx = t; idx < 2048; idx += 512) {
        int k = idx >> 8, d = idx & 255;
        h1[k][d] = fmaxf(part[0][k][d] + part[1][k][d] + db1[d], 0.f);
    }
    __syncthreads();
    // h2 = relu(h1 @ dW2.T + b2): 768 douts
    for (int dout = t; dout < 768; dout += 512) {
        float a[8] = {0.f,0.f,0.f,0.f,0.f,0.f,0.f,0.f};
        #pragma unroll 4
        for (int j = 0; j < 256; ++j) {
            float wv = dW2T[j * 768 + dout];
            #pragma unroll
            for (int k = 0; k < 8; ++k) a[k] += h1[k][j] * wv;
        }
        #pragma unroll
        for (int k = 0; k < 8; ++k) h2[k][dout] = fmaxf(a[k] + db2[dout], 0.f);
    }
    __syncthreads();
    // sf = h2 @ dW3.T + b3 (this block's 384-col half)
    if (t < 384) {
        int dout = half * 384 + t;
        float a[8] = {0.f,0.f,0.f,0.f,0.f,0.f,0.f,0.f};
        #pragma unroll 4
        for (int j = 0; j < 768; ++j) {
            float wv = dW3T[j * 768 + dout];
            #pragma unroll
            for (int k = 0; k < 8; ++k) a[k] += h2[k][j] * wv;
        }
        #pragma unroll
        for (int k = 0; k < 8; ++k)
            sf[((size_t)b * 8 + k) * 768 + dout] = a[k] + db3[dout];
    }
}

// ---------------- K5: fused recon + squared-error partial sums ----------------
__global__ __launch_bounds__(256) void recon_loss_k(
    const float* __restrict__ feats, const float* __restrict__ attnv,
    const float* __restrict__ sf, float* __restrict__ partials) {

    __shared__ float sfl[8][768];
    __shared__ float al[49][8];
    __shared__ float wred[4];
    int b = blockIdx.x, qd = blockIdx.y, t = threadIdx.x;
    for (int idx = t; idx < 8 * 768; idx += 256)
        ((float*)sfl)[idx] = sf[(size_t)b * 8 * 768 + idx];
    int n0 = qd * 49;
    for (int idx = t; idx < 49 * 8; idx += 256)
        ((float*)al)[idx] = attnv[((size_t)b * N_ + n0) * 8 + idx];
    __syncthreads();
    float acc = 0.f;
    for (int nl = 0; nl < 49; ++nl) {
        float a0 = al[nl][0], a1 = al[nl][1], a2 = al[nl][2], a3 = al[nl][3];
        float a4 = al[nl][4], a5 = al[nl][5], a6 = al[nl][6], a7 = al[nl][7];
        const float* frow = feats + ((size_t)(b * N_ + n0 + nl)) * E_;
        for (int c = t; c < E_; c += 256) {
            float r = sfl[0][c]*a0 + sfl[1][c]*a1 + sfl[2][c]*a2 + sfl[3][c]*a3
                    + sfl[4][c]*a4 + sfl[5][c]*a5 + sfl[6][c]*a6 + sfl[7][c]*a7;
            float d = r - frow[c];
            acc += d * d;
        }
    }
    acc = wave_red_sum64(acc);
    int lane = t & 63, w = t >> 6;
    if (lane == 0) wred[w] = acc;
    __syncthreads();
    if (t == 0) partials[b * 4 + qd] = wred[0] + wred[1] + wred[2] + wred[3];
}

__global__ __launch_bounds__(512) void loss_final_k(const float* __restrict__ partials,
                                                    float* __restrict__ out) {
    __shared__ float wred[8];
    int t = threadIdx.x;
    float v = partials[t];
    v = wave_red_sum64(v);
    if ((t & 63) == 0) wred[t >> 6] = v;
    __syncthreads();
    if (t == 0) {
        float s = 0.f;
        #pragma unroll
        for (int i = 0; i < 8; ++i) s += wred[i];
        out[0] = s / (float)(B_ * N_ * E_);
    }
}

// ---------------- launch ----------------
extern "C" void kernel_launch(void* const* d_in, const int* in_sizes, int n_in,
                              void* d_out, int out_size, void* d_ws, size_t ws_size,
                              hipStream_t stream) {
    (void)in_sizes; (void)n_in; (void)out_size; (void)ws_size;
    const float* feats     = (const float*)d_in[0];
    const float* noise     = (const float*)d_in[1];
    const float* ln_in_g   = (const float*)d_in[2];
    const float* ln_in_b   = (const float*)d_in[3];
    const float* ln_slot_g = (const float*)d_in[4];
    const float* ln_slot_b = (const float*)d_in[5];
    const float* ln_out_g  = (const float*)d_in[6];
    const float* ln_out_b  = (const float*)d_in[7];
    const float* ln_dec_g  = (const float*)d_in[8];
    const float* ln_dec_b  = (const float*)d_in[9];
    const float* mu        = (const float*)d_in[10];
    const float* log_sigma = (const float*)d_in[11];
    const float* Wk        = (const float*)d_in[12];
    const float* Wq        = (const float*)d_in[13];
    const float* Wv        = (const float*)d_in[14];
    const float* W_ih      = (const float*)d_in[15];
    const float* W_hh      = (const float*)d_in[16];
    const float* b_ih      = (const float*)d_in[17];
    const float* b_hh      = (const float*)d_in[18];
    const float* mlp_W1    = (const float*)d_in[19];
    const float* mlp_b1    = (const float*)d_in[20];
    const float* mlp_W2    = (const float*)d_in[21];
    const float* mlp_b2    = (const float*)d_in[22];
    const float* dec_W1    = (const float*)d_in[23];
    const float* dec_b1    = (const float*)d_in[24];
    const float* dec_W2    = (const float*)d_in[25];
    const float* dec_b2    = (const float*)d_in[26];
    const float* dec_W3    = (const float*)d_in[27];
    const float* dec_b3    = (const float*)d_in[28];

    float* ws    = (float*)d_ws;
    float* stats = ws + OFF_STATS;
    float* WqT   = ws + OFF_WQT;
    float* WihT  = ws + OFF_WIHT;
    float* WhhT  = ws + OFF_WHHT;
    float* W1T   = ws + OFF_W1T;
    float* W2T   = ws + OFF_W2T;
    float* dW1T  = ws + OFF_DW1T;
    float* dW2T  = ws + OFF_DW2T;
    float* dW3T  = ws + OFF_DW3T;
    float* kp    = ws + OFF_KP;
    float* vp    = ws + OFF_VP;
    float* sf    = ws + OFF_SF;
    float* parts = ws + OFF_PART;

    float* out_slots = (float*)d_out;               // [128,8,128]
    float* out_attn  = out_slots + 131072;          // [128,196,8]
    float* out_loss  = out_slots + 331776;          // scalar

    dim3 tb(32, 8);
    tK<<<dim3(4, 4),   tb, 0, stream>>>(Wq,     WqT,  128, 128);
    tK<<<dim3(4, 12),  tb, 0, stream>>>(W_ih,   WihT, 384, 128);
    tK<<<dim3(4, 12),  tb, 0, stream>>>(W_hh,   WhhT, 384, 128);
    tK<<<dim3(4, 4),   tb, 0, stream>>>(mlp_W1, W1T,  128, 128);
    tK<<<dim3(4, 4),   tb, 0, stream>>>(mlp_W2, W2T,  128, 128);
    tK<<<dim3(4, 8),   tb, 0, stream>>>(dec_W1, dW1T, 256, 128);
    tK<<<dim3(8, 24),  tb, 0, stream>>>(dec_W2, dW2T, 768, 256);
    tK<<<dim3(24, 24), tb, 0, stream>>>(dec_W3, dW3T, 768, 768);

    ln_stats_k<<<BNR / 4, 256, 0, stream>>>(feats, stats);
    proj_k<<<BNR / 64, 256, 0, stream>>>(feats, stats, ln_in_g, ln_in_b, Wk, Wv, kp, vp);
    slot_iter_k<<<B_, 512, 0, stream>>>(noise, ln_slot_g, ln_slot_b, ln_out_g, ln_out_b,
                                        mu, log_sigma, WqT, WihT, WhhT, b_ih, b_hh,
                                        W1T, mlp_b1, W2T, mlp_b2, kp, vp,
                                        out_slots, out_attn);
    decoder_k<<<dim3(B_, 2), 512, 0, stream>>>(ln_dec_g, ln_dec_b, dW1T, dec_b1,
                                               dW2T, dec_b2, dW3T, dec_b3,
                                               out_slots, sf);
    recon_loss_k<<<dim3(B_, 4), 256, 0, stream>>>(feats, out_attn, sf, parts);
    loss_final_k<<<1, 512, 0, stream>>>(parts, out_loss);
}

// Round 3
// 376.926 us; speedup vs baseline: 1.3525x; 1.3525x over previous
//
#include <hip/hip_runtime.h>
#include <hip/hip_bf16.h>
#include <math.h>

// ---------------- problem constants ----------------
#define B_    128
#define N_    196
#define E_    768
#define K_    8
#define D_    128
#define BNR   (B_*N_)        // 25088 rows
#define ITERS 5

// ws layout (in float units)
#define OFF_KP    0          // 25088*128
#define OFF_VP    3211264    // 25088*128
#define OFF_SF    6422528    // 1024*768
#define OFF_PART  7208960    // 512
#define OFF_WQT   7209472    // 128*128
#define OFF_WIHT  7225856    // 128*384
#define OFF_WHHT  7275008    // 128*384
#define OFF_W1T   7324160    // 128*128
#define OFF_W2T   7340544    // 128*128
#define OFF_DW1T  7356928    // 128*256
#define OFF_DW2T  7389696    // 256*768
#define OFF_DW3T  7586304    // 768*768
#define OFF_ABF   8176128    // bf16[25088*768] stored as ushort
#define OFF_WB    17809920   // bf16[256*768]

typedef __attribute__((ext_vector_type(8))) short bf16x8;
typedef __attribute__((ext_vector_type(4))) float f32x4;

__device__ __forceinline__ float wave_red_sum64(float v) {
    #pragma unroll
    for (int o = 32; o > 0; o >>= 1) v += __shfl_xor(v, o);
    return v;
}

__device__ __forceinline__ unsigned short f2bf(float v) {
    union { float f; unsigned int u; } c; c.f = v;
    unsigned int u = c.u + 0x7fffu + ((c.u >> 16) & 1u);  // RNE
    return (unsigned short)(u >> 16);
}

__device__ __forceinline__ void gl_lds16(const void* g, void* l) {
    __builtin_amdgcn_global_load_lds(
        (const __attribute__((address_space(1))) unsigned int*)g,
        (__attribute__((address_space(3))) unsigned int*)l, 16, 0, 0);
}

// ---------------- K0a: fused all-weights transpose ----------------
struct TP { const float* s; float* d; int R; int C; int t0; };
struct TArgs { TP m[8]; };

__global__ __launch_bounds__(256) void tAll(TArgs a) {
    __shared__ float tile[32][33];
    int bid = blockIdx.x;
    int i = 0;
    #pragma unroll
    for (int j = 1; j < 8; ++j) if (bid >= a.m[j].t0) i = j;
    const float* src = a.m[i].s;
    float* dst = a.m[i].d;
    int R = a.m[i].R, C = a.m[i].C;
    int tid = bid - a.m[i].t0;
    int tilesC = C >> 5;
    int tr = tid / tilesC, tc = tid - tr * tilesC;
    int bx = tc * 32, by = tr * 32;
    int tx = threadIdx.x, ty = threadIdx.y;  // (32,8)
    #pragma unroll
    for (int q = 0; q < 32; q += 8)
        tile[ty + q][tx] = src[(size_t)(by + ty + q) * C + (bx + tx)];
    __syncthreads();
    #pragma unroll
    for (int q = 0; q < 32; q += 8)
        dst[(size_t)(bx + ty + q) * R + (by + tx)] = tile[tx][ty + q];
}

// ---------------- K0b: Wk|Wv -> bf16 (kscale folded into Wk rows) ----------------
__global__ __launch_bounds__(256) void wconv_k(const float* __restrict__ Wk,
                                               const float* __restrict__ Wv,
                                               unsigned short* __restrict__ Wb) {
    int idx = (blockIdx.x * 256 + threadIdx.x) * 8;  // grid 96 -> 196608 elems
    int n = idx / 768, c = idx - n * 768;
    const float* src = (n < 128) ? (Wk + (size_t)n * 768 + c)
                                 : (Wv + (size_t)(n - 128) * 768 + c);
    float sc = (n < 128) ? 0.08838834764831845f : 1.0f;
    float4 v0 = *(const float4*)src;
    float4 v1 = *(const float4*)(src + 4);
    ushort4 o0, o1;
    o0.x = f2bf(v0.x * sc); o0.y = f2bf(v0.y * sc);
    o0.z = f2bf(v0.z * sc); o0.w = f2bf(v0.w * sc);
    o1.x = f2bf(v1.x * sc); o1.y = f2bf(v1.y * sc);
    o1.z = f2bf(v1.z * sc); o1.w = f2bf(v1.w * sc);
    *(ushort4*)(Wb + idx) = o0;
    *(ushort4*)(Wb + idx + 4) = o1;
}

// ---------------- K1: one-pass LayerNorm(features) -> bf16 ----------------
__global__ __launch_bounds__(256) void ln_bf16_k(const float* __restrict__ f,
                                                 const float* __restrict__ g,
                                                 const float* __restrict__ bv,
                                                 unsigned short* __restrict__ out) {
    int wid = blockIdx.x * 4 + (threadIdx.x >> 6);   // one wave per row
    int lane = threadIdx.x & 63;
    const float* row = f + (size_t)wid * E_;
    float4 x[3];
    float s = 0.f, s2 = 0.f;
    #pragma unroll
    for (int c = 0; c < 3; ++c) {
        x[c] = *(const float4*)(row + c * 256 + lane * 4);
        s  += x[c].x + x[c].y + x[c].z + x[c].w;
        s2 += x[c].x * x[c].x + x[c].y * x[c].y + x[c].z * x[c].z + x[c].w * x[c].w;
    }
    s  = wave_red_sum64(s);
    s2 = wave_red_sum64(s2);
    float m = s * (1.f / E_);
    float rs = rsqrtf(s2 * (1.f / E_) - m * m + 1e-5f);
    #pragma unroll
    for (int c = 0; c < 3; ++c) {
        float4 g4 = *(const float4*)(g + c * 256 + lane * 4);
        float4 b4 = *(const float4*)(bv + c * 256 + lane * 4);
        ushort4 o;
        o.x = f2bf((x[c].x - m) * rs * g4.x + b4.x);
        o.y = f2bf((x[c].y - m) * rs * g4.y + b4.y);
        o.z = f2bf((x[c].z - m) * rs * g4.z + b4.z);
        o.w = f2bf((x[c].w - m) * rs * g4.w + b4.w);
        *(ushort4*)(out + (size_t)wid * E_ + c * 256 + lane * 4) = o;
    }
}

// ---------------- K2: bf16 MFMA GEMM: C[25088,256] = Abf @ Wb^T ----------------
// grid (196, 2): y=0 -> kp cols 0..127, y=1 -> vp. 128x128 tile, BK=64,
// 4 waves (2x2), 64x64 per wave, 16x16x32 MFMA, XOR chunk-swizzled LDS.
__global__ __launch_bounds__(256) void mfma_proj_k(const unsigned short* __restrict__ Abf,
                                                   const unsigned short* __restrict__ Wb,
                                                   float* __restrict__ kp,
                                                   float* __restrict__ vp) {
    __shared__ __align__(16) unsigned short As[128 * 64];
    __shared__ __align__(16) unsigned short Bs[128 * 64];
    const int t = threadIdx.x, w = t >> 6, l = t & 63;
    const int m0 = blockIdx.x * 128;
    const int n0 = blockIdx.y * 128;
    const int wr = w >> 1, wc = w & 1;
    const int fr = l & 15, kq = l >> 4;     // fragment row/col, k-quarter
    f32x4 acc[4][4];
    #pragma unroll
    for (int mi = 0; mi < 4; ++mi)
        #pragma unroll
        for (int nj = 0; nj < 4; ++nj) acc[mi][nj] = (f32x4){0.f, 0.f, 0.f, 0.f};

    // staging geometry: tile = 128 rows x 8 chunks(16B); per wave 4 calls.
    const int ci_l = l;  // lane part of chunk index
    for (int ks = 0; ks < E_; ks += 64) {
        __syncthreads();
        #pragma unroll
        for (int j = 0; j < 4; ++j) {
            int ci = (w << 8) + (j << 6) + ci_l;
            int r = ci >> 3, c = ci & 7;
            int cg = c ^ (r & 7);   // inverse swizzle on global source
            const unsigned short* ga = Abf + (size_t)(m0 + r) * E_ + ks + cg * 8;
            const unsigned short* gb = Wb  + (size_t)(n0 + r) * E_ + ks + cg * 8;
            gl_lds16(ga, As + (size_t)((w << 8) + (j << 6)) * 8);
            gl_lds16(gb, Bs + (size_t)((w << 8) + (j << 6)) * 8);
        }
        __syncthreads();  // drains vmcnt(0)
        #pragma unroll
        for (int kk = 0; kk < 2; ++kk) {
            bf16x8 af[4], bfr[4];
            int kci = kk * 4 + kq;
            int ch = kci ^ (fr & 7);   // swizzled read
            #pragma unroll
            for (int mi = 0; mi < 4; ++mi) {
                int R = wr * 64 + mi * 16 + fr;
                af[mi] = *(const bf16x8*)(As + R * 64 + ch * 8);
            }
            #pragma unroll
            for (int nj = 0; nj < 4; ++nj) {
                int R = wc * 64 + nj * 16 + fr;
                bfr[nj] = *(const bf16x8*)(Bs + R * 64 + ch * 8);
            }
            #pragma unroll
            for (int mi = 0; mi < 4; ++mi)
                #pragma unroll
                for (int nj = 0; nj < 4; ++nj)
                    acc[mi][nj] = __builtin_amdgcn_mfma_f32_16x16x32_bf16(
                        af[mi], bfr[nj], acc[mi][nj], 0, 0, 0);
        }
    }
    float* outp = (n0 == 0) ? kp : vp;
    #pragma unroll
    for (int mi = 0; mi < 4; ++mi) {
        int row = m0 + wr * 64 + mi * 16 + kq * 4;   // C/D: row=(l>>4)*4+reg
        #pragma unroll
        for (int nj = 0; nj < 4; ++nj) {
            int col = wc * 64 + nj * 16 + fr;        // C/D: col=l&15
            #pragma unroll
            for (int r = 0; r < 4; ++r)
                outp[(size_t)(row + r) * D_ + col] = acc[mi][nj][r];
        }
    }
}

// ---- helpers for the iteration kernel ----
__device__ __forceinline__ void ln_8x128(const float (*src)[128], float (*dst)[128],
                                         const float* __restrict__ g,
                                         const float* __restrict__ bvec, int t) {
    int k = t >> 6, lane = t & 63;
    float x0 = src[k][lane], x1 = src[k][lane + 64];
    float s  = wave_red_sum64(x0 + x1);
    float s2 = wave_red_sum64(x0 * x0 + x1 * x1);
    float m = s * (1.f / 128.f);
    float var = s2 * (1.f / 128.f) - m * m;
    float rs = rsqrtf(var + 1e-5f);
    dst[k][lane]      = (x0 - m) * rs * g[lane]      + bvec[lane];
    dst[k][lane + 64] = (x1 - m) * rs * g[lane + 64] + bvec[lane + 64];
}

__device__ __forceinline__ void mv128(const float (*in)[128], const float* __restrict__ WT,
                                      float (*part)[8][128], int t) {
    int dout = t & 127, jc = t >> 7;
    float a[8] = {0.f,0.f,0.f,0.f,0.f,0.f,0.f,0.f};
    int j0 = jc * 32;
    #pragma unroll 4
    for (int j = j0; j < j0 + 32; ++j) {
        float wv = WT[j * 128 + dout];
        #pragma unroll
        for (int k = 0; k < 8; ++k) a[k] += in[k][j] * wv;
    }
    #pragma unroll
    for (int k = 0; k < 8; ++k) part[jc][k][dout] = a[k];
}

// ---------------- K3: persistent per-batch slot-attention iterations ----------------
__global__ __launch_bounds__(512) void slot_iter_k(
    const float* __restrict__ noise,
    const float* __restrict__ lsg, const float* __restrict__ lsb,
    const float* __restrict__ log_, const float* __restrict__ lob,
    const float* __restrict__ mup, const float* __restrict__ lsig,
    const float* __restrict__ WqT, const float* __restrict__ WihT,
    const float* __restrict__ WhhT,
    const float* __restrict__ bih, const float* __restrict__ bhh,
    const float* __restrict__ W1T, const float* __restrict__ mb1,
    const float* __restrict__ W2T, const float* __restrict__ mb2,
    const float* __restrict__ kp, const float* __restrict__ vp,
    float* __restrict__ out_slots, float* __restrict__ out_attn) {

    __shared__ float slots[8][128];
    __shared__ float sln[8][128];
    __shared__ float qb[8][128];
    __shared__ float upd[8][128];
    __shared__ float attn[196][9];
    __shared__ float gi[8][384];
    __shared__ float gh[8][384];
    __shared__ float part[4][8][128];
    __shared__ float colsum[8];

    int b = blockIdx.x, t = threadIdx.x;
    int lane = t & 63, w = t >> 6;
    const float* kpb = kp + (size_t)b * N_ * D_;
    const float* vpb = vp + (size_t)b * N_ * D_;

    for (int idx = t; idx < 1024; idx += 512) {
        int d = idx & 127;
        slots[idx >> 7][d] = noise[(size_t)b * 1024 + idx] * expf(lsig[d]) + mup[d];
    }

    for (int it = 0; it < ITERS; ++it) {
        __syncthreads();
        ln_8x128(slots, sln, lsg, lsb, t);
        __syncthreads();
        mv128(sln, WqT, part, t);
        __syncthreads();
        for (int idx = t; idx < 1024; idx += 512) {
            int k = idx >> 7, d = idx & 127;
            qb[k][d] = part[0][k][d] + part[1][k][d] + part[2][k][d] + part[3][k][d];
        }
        __syncthreads();
        {
            int sub = lane >> 3, dgi = lane & 7, dg = dgi * 16;
            bool lastit = (it == ITERS - 1);
            #pragma unroll
            for (int p = 0; p < 4; ++p) {
                int n = p * 64 + w * 8 + sub;
                if (n < N_) {
                    float kv[16];
                    *(float4*)&kv[0]  = *(const float4*)(kpb + (size_t)n * D_ + dg);
                    *(float4*)&kv[4]  = *(const float4*)(kpb + (size_t)n * D_ + dg + 4);
                    *(float4*)&kv[8]  = *(const float4*)(kpb + (size_t)n * D_ + dg + 8);
                    *(float4*)&kv[12] = *(const float4*)(kpb + (size_t)n * D_ + dg + 12);
                    float l8[8];
                    #pragma unroll
                    for (int k = 0; k < 8; ++k) {
                        float acc = 0.f;
                        #pragma unroll
                        for (int i = 0; i < 16; ++i) acc += kv[i] * qb[k][dg + i];
                        l8[k] = acc;
                    }
                    #pragma unroll
                    for (int o = 1; o < 8; o <<= 1) {
                        #pragma unroll
                        for (int k = 0; k < 8; ++k) l8[k] += __shfl_xor(l8[k], o);
                    }
                    float m = l8[0];
                    #pragma unroll
                    for (int k = 1; k < 8; ++k) m = fmaxf(m, l8[k]);
                    float e[8], s = 0.f;
                    #pragma unroll
                    for (int k = 0; k < 8; ++k) { e[k] = expf(l8[k] - m); s += e[k]; }
                    float inv = 1.f / s;
                    if (dgi == 0) {
                        #pragma unroll
                        for (int k = 0; k < 8; ++k) attn[n][k] = e[k] * inv;
                        if (lastit) {
                            *(float4*)(out_attn + ((size_t)b * N_ + n) * 8) =
                                make_float4(e[0]*inv, e[1]*inv, e[2]*inv, e[3]*inv);
                            *(float4*)(out_attn + ((size_t)b * N_ + n) * 8 + 4) =
                                make_float4(e[4]*inv, e[5]*inv, e[6]*inv, e[7]*inv);
                        }
                    }
                }
            }
        }
        __syncthreads();
        {
            float s = 0.f;
            for (int n = lane; n < N_; n += 64) s += attn[n][w] + 1e-8f;
            s = wave_red_sum64(s);
            if (lane == 0) colsum[w] = s;
        }
        __syncthreads();
        for (int idx = t; idx < N_ * 8; idx += 512) {
            int n = idx >> 3, k = idx & 7;
            attn[n][k] = (attn[n][k] + 1e-8f) / colsum[k];
        }
        __syncthreads();
        {
            int dout = t & 127, nc = t >> 7;
            float a[8] = {0.f,0.f,0.f,0.f,0.f,0.f,0.f,0.f};
            int n0 = nc * 49;
            for (int n = n0; n < n0 + 49; ++n) {
                float v = vpb[(size_t)n * D_ + dout];
                #pragma unroll
                for (int k = 0; k < 8; ++k) a[k] += attn[n][k] * v;
            }
            #pragma unroll
            for (int k = 0; k < 8; ++k) part[nc][k][dout] = a[k];
        }
        __syncthreads();
        for (int idx = t; idx < 1024; idx += 512) {
            int k = idx >> 7, d = idx & 127;
            upd[k][d] = part[0][k][d] + part[1][k][d] + part[2][k][d] + part[3][k][d];
        }
        __syncthreads();
        if (t < 384) {
            float gia[8] = {0.f,0.f,0.f,0.f,0.f,0.f,0.f,0.f};
            float gha[8] = {0.f,0.f,0.f,0.f,0.f,0.f,0.f,0.f};
            #pragma unroll 4
            for (int j = 0; j < 128; ++j) {
                float wi = WihT[j * 384 + t];
                float wh = WhhT[j * 384 + t];
                #pragma unroll
                for (int k = 0; k < 8; ++k) {
                    gia[k] += upd[k][j] * wi;
                    gha[k] += slots[k][j] * wh;
                }
            }
            float bi = bih[t], bh = bhh[t];
            #pragma unroll
            for (int k = 0; k < 8; ++k) {
                gi[k][t] = gia[k] + bi;
                gh[k][t] = gha[k] + bh;
            }
        }
        __syncthreads();
        for (int idx = t; idx < 1024; idx += 512) {
            int k = idx >> 7, d = idx & 127;
            float ir = gi[k][d], iz = gi[k][128 + d], inn = gi[k][256 + d];
            float hr = gh[k][d], hz = gh[k][128 + d], hn = gh[k][256 + d];
            float r = 1.f / (1.f + expf(-(ir + hr)));
            float z = 1.f / (1.f + expf(-(iz + hz)));
            float nn = tanhf(inn + r * hn);
            float h = slots[k][d];
            slots[k][d] = (1.f - z) * nn + z * h;
        }
        __syncthreads();
        ln_8x128(slots, sln, log_, lob, t);
        __syncthreads();
        mv128(sln, W1T, part, t);
        __syncthreads();
        for (int idx = t; idx < 1024; idx += 512) {
            int k = idx >> 7, d = idx & 127;
            float v = part[0][k][d] + part[1][k][d] + part[2][k][d] + part[3][k][d] + mb1[d];
            qb[k][d] = fmaxf(v, 0.f);
        }
        __syncthreads();
        mv128(qb, W2T, part, t);
        __syncthreads();
        for (int idx = t; idx < 1024; idx += 512) {
            int k = idx >> 7, d = idx & 127;
            slots[k][d] += part[0][k][d] + part[1][k][d] + part[2][k][d] + part[3][k][d] + mb2[d];
        }
    }
    __syncthreads();
    for (int idx = t; idx < 1024; idx += 512)
        out_slots[(size_t)b * 1024 + idx] = slots[idx >> 7][idx & 127];
}

// ---------------- K4: decoder MLP per batch ----------------
__global__ __launch_bounds__(512) void decoder_k(
    const float* __restrict__ ldg_, const float* __restrict__ ldb,
    const float* __restrict__ dW1T, const float* __restrict__ db1,
    const float* __restrict__ dW2T, const float* __restrict__ db2,
    const float* __restrict__ dW3T, const float* __restrict__ db3,
    const float* __restrict__ slots_in, float* __restrict__ sf) {

    __shared__ float s[8][128];
    __shared__ float h1[8][256];
    __shared__ float h2[8][768];
    __shared__ float part[2][8][256];
    int b = blockIdx.x, half = blockIdx.y, t = threadIdx.x;
    int lane = t & 63, w = t >> 6;

    {
        float x0 = slots_in[(size_t)b * 1024 + w * 128 + lane];
        float x1 = slots_in[(size_t)b * 1024 + w * 128 + lane + 64];
        float su  = wave_red_sum64(x0 + x1);
        float su2 = wave_red_sum64(x0 * x0 + x1 * x1);
        float m = su * (1.f / 128.f);
        float var = su2 * (1.f / 128.f) - m * m;
        float rs = rsqrtf(var + 1e-5f);
        s[w][lane]      = (x0 - m) * rs * ldg_[lane]      + ldb[lane];
        s[w][lane + 64] = (x1 - m) * rs * ldg_[lane + 64] + ldb[lane + 64];
    }
    __syncthreads();
    {
        int dout = t & 255, jc = t >> 8;
        float a[8] = {0.f,0.f,0.f,0.f,0.f,0.f,0.f,0.f};
        int j0 = jc * 64;
        #pragma unroll 4
        for (int j = j0; j < j0 + 64; ++j) {
            float wv = dW1T[j * 256 + dout];
            #pragma unroll
            for (int k = 0; k < 8; ++k) a[k] += s[k][j] * wv;
        }
        #pragma unroll
        for (int k = 0; k < 8; ++k) part[jc][k][dout] = a[k];
    }
    __syncthreads();
    for (int idx = t; idx < 2048; idx += 512) {
        int k = idx >> 8, d = idx & 255;
        h1[k][d] = fmaxf(part[0][k][d] + part[1][k][d] + db1[d], 0.f);
    }
    __syncthreads();
    for (int dout = t; dout < 768; dout += 512) {
        float a[8] = {0.f,0.f,0.f,0.f,0.f,0.f,0.f,0.f};
        #pragma unroll 4
        for (int j = 0; j < 256; ++j) {
            float wv = dW2T[j * 768 + dout];
            #pragma unroll
            for (int k = 0; k < 8; ++k) a[k] += h1[k][j] * wv;
        }
        #pragma unroll
        for (int k = 0; k < 8; ++k) h2[k][dout] = fmaxf(a[k] + db2[dout], 0.f);
    }
    __syncthreads();
    if (t < 384) {
        int dout = half * 384 + t;
        float a[8] = {0.f,0.f,0.f,0.f,0.f,0.f,0.f,0.f};
        #pragma unroll 4
        for (int j = 0; j < 768; ++j) {
            float wv = dW3T[j * 768 + dout];
            #pragma unroll
            for (int k = 0; k < 8; ++k) a[k] += h2[k][j] * wv;
        }
        #pragma unroll
        for (int k = 0; k < 8; ++k)
            sf[((size_t)b * 8 + k) * 768 + dout] = a[k] + db3[dout];
    }
}

// ---------------- K5: fused recon + squared-error partial sums ----------------
__global__ __launch_bounds__(256) void recon_loss_k(
    const float* __restrict__ feats, const float* __restrict__ attnv,
    const float* __restrict__ sf, float* __restrict__ partials) {

    __shared__ float sfl[8][768];
    __shared__ float al[49][8];
    __shared__ float wred[4];
    int b = blockIdx.x, qd = blockIdx.y, t = threadIdx.x;
    for (int idx = t; idx < 8 * 768; idx += 256)
        ((float*)sfl)[idx] = sf[(size_t)b * 8 * 768 + idx];
    int n0 = qd * 49;
    for (int idx = t; idx < 49 * 8; idx += 256)
        ((float*)al)[idx] = attnv[((size_t)b * N_ + n0) * 8 + idx];
    __syncthreads();
    float acc = 0.f;
    for (int nl = 0; nl < 49; ++nl) {
        float a0 = al[nl][0], a1 = al[nl][1], a2 = al[nl][2], a3 = al[nl][3];
        float a4 = al[nl][4], a5 = al[nl][5], a6 = al[nl][6], a7 = al[nl][7];
        const float* frow = feats + ((size_t)(b * N_ + n0 + nl)) * E_;
        for (int c = t; c < E_; c += 256) {
            float r = sfl[0][c]*a0 + sfl[1][c]*a1 + sfl[2][c]*a2 + sfl[3][c]*a3
                    + sfl[4][c]*a4 + sfl[5][c]*a5 + sfl[6][c]*a6 + sfl[7][c]*a7;
            float d = r - frow[c];
            acc += d * d;
        }
    }
    acc = wave_red_sum64(acc);
    int lane = t & 63, w = t >> 6;
    if (lane == 0) wred[w] = acc;
    __syncthreads();
    if (t == 0) partials[b * 4 + qd] = wred[0] + wred[1] + wred[2] + wred[3];
}

__global__ __launch_bounds__(512) void loss_final_k(const float* __restrict__ partials,
                                                    float* __restrict__ out) {
    __shared__ float wred[8];
    int t = threadIdx.x;
    float v = partials[t];
    v = wave_red_sum64(v);
    if ((t & 63) == 0) wred[t >> 6] = v;
    __syncthreads();
    if (t == 0) {
        float s = 0.f;
        #pragma unroll
        for (int i = 0; i < 8; ++i) s += wred[i];
        out[0] = s / (float)(B_ * N_ * E_);
    }
}

// ---------------- launch ----------------
extern "C" void kernel_launch(void* const* d_in, const int* in_sizes, int n_in,
                              void* d_out, int out_size, void* d_ws, size_t ws_size,
                              hipStream_t stream) {
    (void)in_sizes; (void)n_in; (void)out_size; (void)ws_size;
    const float* feats     = (const float*)d_in[0];
    const float* noise     = (const float*)d_in[1];
    const float* ln_in_g   = (const float*)d_in[2];
    const float* ln_in_b   = (const float*)d_in[3];
    const float* ln_slot_g = (const float*)d_in[4];
    const float* ln_slot_b = (const float*)d_in[5];
    const float* ln_out_g  = (const float*)d_in[6];
    const float* ln_out_b  = (const float*)d_in[7];
    const float* ln_dec_g  = (const float*)d_in[8];
    const float* ln_dec_b  = (const float*)d_in[9];
    const float* mu        = (const float*)d_in[10];
    const float* log_sigma = (const float*)d_in[11];
    const float* Wk        = (const float*)d_in[12];
    const float* Wq        = (const float*)d_in[13];
    const float* Wv        = (const float*)d_in[14];
    const float* W_ih      = (const float*)d_in[15];
    const float* W_hh      = (const float*)d_in[16];
    const float* b_ih      = (const float*)d_in[17];
    const float* b_hh      = (const float*)d_in[18];
    const float* mlp_W1    = (const float*)d_in[19];
    const float* mlp_b1    = (const float*)d_in[20];
    const float* mlp_W2    = (const float*)d_in[21];
    const float* mlp_b2    = (const float*)d_in[22];
    const float* dec_W1    = (const float*)d_in[23];
    const float* dec_b1    = (const float*)d_in[24];
    const float* dec_W2    = (const float*)d_in[25];
    const float* dec_b2    = (const float*)d_in[26];
    const float* dec_W3    = (const float*)d_in[27];
    const float* dec_b3    = (const float*)d_in[28];

    float* ws    = (float*)d_ws;
    float* kp    = ws + OFF_KP;
    float* vp    = ws + OFF_VP;
    float* sf    = ws + OFF_SF;
    float* parts = ws + OFF_PART;
    float* WqT   = ws + OFF_WQT;
    float* WihT  = ws + OFF_WIHT;
    float* WhhT  = ws + OFF_WHHT;
    float* W1T   = ws + OFF_W1T;
    float* W2T   = ws + OFF_W2T;
    float* dW1T  = ws + OFF_DW1T;
    float* dW2T  = ws + OFF_DW2T;
    float* dW3T  = ws + OFF_DW3T;
    unsigned short* Abf = (unsigned short*)(ws + OFF_ABF);
    unsigned short* Wb  = (unsigned short*)(ws + OFF_WB);

    float* out_slots = (float*)d_out;               // [128,8,128]
    float* out_attn  = out_slots + 131072;          // [128,196,8]
    float* out_loss  = out_slots + 331776;          // scalar

    // fused transposes: tile ranges {0,16,64,112,128,144,176,368}, total 944
    TArgs ta;
    ta.m[0] = {Wq,     WqT,  128, 128, 0};
    ta.m[1] = {W_ih,   WihT, 384, 128, 16};
    ta.m[2] = {W_hh,   WhhT, 384, 128, 64};
    ta.m[3] = {mlp_W1, W1T,  128, 128, 112};
    ta.m[4] = {mlp_W2, W2T,  128, 128, 128};
    ta.m[5] = {dec_W1, dW1T, 256, 128, 144};
    ta.m[6] = {dec_W2, dW2T, 768, 256, 176};
    ta.m[7] = {dec_W3, dW3T, 768, 768, 368};
    tAll<<<944, dim3(32, 8), 0, stream>>>(ta);

    wconv_k<<<96, 256, 0, stream>>>(Wk, Wv, Wb);
    ln_bf16_k<<<BNR / 4, 256, 0, stream>>>(feats, ln_in_g, ln_in_b, Abf);
    mfma_proj_k<<<dim3(BNR / 128, 2), 256, 0, stream>>>(Abf, Wb, kp, vp);

    slot_iter_k<<<B_, 512, 0, stream>>>(noise, ln_slot_g, ln_slot_b, ln_out_g, ln_out_b,
                                        mu, log_sigma, WqT, WihT, WhhT, b_ih, b_hh,
                                        W1T, mlp_b1, W2T, mlp_b2, kp, vp,
                                        out_slots, out_attn);
    decoder_k<<<dim3(B_, 2), 512, 0, stream>>>(ln_dec_g, ln_dec_b, dW1T, dec_b1,
                                               dW2T, dec_b2, dW3T, dec_b3,
                                               out_slots, sf);
    recon_loss_k<<<dim3(B_, 4), 256, 0, stream>>>(feats, out_attn, sf, parts);
    loss_final_k<<<1, 512, 0, stream>>>(parts, out_loss);
}

// Round 4
// 292.615 us; speedup vs baseline: 1.7422x; 1.2881x over previous
//
#include <hip/hip_runtime.h>
#include <hip/hip_bf16.h>
#include <math.h>

// ---------------- problem constants ----------------
#define B_    128
#define N_    196
#define E_    768
#define K_    8
#define D_    128
#define BNR   (B_*N_)        // 25088 rows
#define ITERS 5

// ws layout (float units)
#define OFF_SF     0          // 1024*768
#define OFF_PART   786432     // 512
#define OFF_DW1T   786944     // 128*256
#define OFF_DW2T   819712     // 256*768
#define OFF_DW3T   1016320    // 768*768
#define OFF_WBF    1606144    // ushort region: 344064 ushorts (see cum offsets below)
#define OFF_KPBF   1778176    // ushort[128*208*128]
#define OFF_VPTBF  3482112    // ushort[128*128*224]
#define OFF_ABF    5317120    // ushort[25088*768]

typedef __attribute__((ext_vector_type(8))) short bf16x8;
typedef __attribute__((ext_vector_type(4))) float f32x4;

#define MFMA16(a, b, c) __builtin_amdgcn_mfma_f32_16x16x32_bf16(a, b, c, 0, 0, 0)

__device__ __forceinline__ float wave_red_sum64(float v) {
    #pragma unroll
    for (int o = 32; o > 0; o >>= 1) v += __shfl_xor(v, o);
    return v;
}

__device__ __forceinline__ unsigned short f2bf(float v) {
    union { float f; unsigned int u; } c; c.f = v;
    unsigned int u = c.u + 0x7fffu + ((c.u >> 16) & 1u);  // RNE
    return (unsigned short)(u >> 16);
}

__device__ __forceinline__ void gl_lds16(const void* g, void* l) {
    __builtin_amdgcn_global_load_lds(
        (const __attribute__((address_space(1))) unsigned int*)g,
        (__attribute__((address_space(3))) unsigned int*)l, 16, 0, 0);
}

// chunk-XOR swizzled LDS addressing (8-bf16 = 16B chunks; XOR low 3 chunk bits with row&7)
__device__ __forceinline__ int swz128(int row, int j) {
    return row * 128 + ((((j >> 3) ^ (row & 7))) << 3) + (j & 7);
}
__device__ __forceinline__ int swz256(int row, int j) {
    return row * 256 + ((((j >> 3) ^ (row & 7))) << 3) + (j & 7);
}
__device__ __forceinline__ bf16x8 ldA128(const unsigned short* base, int fr, int kq, int ks) {
    int ch = (ks * 4 + kq) ^ (fr & 7);
    return *(const bf16x8*)(base + fr * 128 + ch * 8);
}
__device__ __forceinline__ bf16x8 ldA256(const unsigned short* base, int fr, int kq, int ks) {
    int ch = (ks * 4 + kq) ^ (fr & 7);
    return *(const bf16x8*)(base + fr * 256 + ch * 8);
}
__device__ __forceinline__ bf16x8 ldW128(const unsigned short* W, int row, int ks, int kq) {
    return *(const bf16x8*)(W + (size_t)row * 128 + ks * 32 + kq * 8);
}

// ---------------- K0a: decoder-weight transposes (fp32, 3 matrices) ----------------
struct TP { const float* s; float* d; int R; int C; int t0; };
struct T3Args { TP m[3]; };

__global__ __launch_bounds__(256) void tAll(T3Args a) {
    __shared__ float tile[32][33];
    int bid = blockIdx.x;
    int i = 0;
    #pragma unroll
    for (int j = 1; j < 3; ++j) if (bid >= a.m[j].t0) i = j;
    const float* src = a.m[i].s;
    float* dst = a.m[i].d;
    int R = a.m[i].R, C = a.m[i].C;
    int tid = bid - a.m[i].t0;
    int tilesC = C >> 5;
    int tr = tid / tilesC, tc = tid - tr * tilesC;
    int bx = tc * 32, by = tr * 32;
    int tx = threadIdx.x, ty = threadIdx.y;  // (32,8)
    #pragma unroll
    for (int q = 0; q < 32; q += 8)
        tile[ty + q][tx] = src[(size_t)(by + ty + q) * C + (bx + tx)];
    __syncthreads();
    #pragma unroll
    for (int q = 0; q < 32; q += 8)
        dst[(size_t)(bx + ty + q) * R + (by + tx)] = tile[tx][ty + q];
}

// ---------------- K0b: all small weights -> bf16 (row-major, kscale folded into Wk) ----------------
struct WCEnt { const float* s; unsigned short* d; float scale; int t0; };
struct WCArgs { WCEnt m[7]; };

__global__ __launch_bounds__(256) void wconv_all(WCArgs a) {
    int bid = blockIdx.x, i = 0;
    #pragma unroll
    for (int j = 1; j < 7; ++j) if (bid >= a.m[j].t0) i = j;
    int off = (bid - a.m[i].t0) * 2048 + threadIdx.x * 8;
    const float* s = a.m[i].s + off;
    unsigned short* d = a.m[i].d + off;
    float sc = a.m[i].scale;
    float4 v0 = *(const float4*)s, v1 = *(const float4*)(s + 4);
    ushort4 o0, o1;
    o0.x = f2bf(v0.x * sc); o0.y = f2bf(v0.y * sc);
    o0.z = f2bf(v0.z * sc); o0.w = f2bf(v0.w * sc);
    o1.x = f2bf(v1.x * sc); o1.y = f2bf(v1.y * sc);
    o1.z = f2bf(v1.z * sc); o1.w = f2bf(v1.w * sc);
    *(ushort4*)d = o0; *(ushort4*)(d + 4) = o1;
}

// ---------------- K0c: zero the kp_bf / vpT_bf padding (token pads must be 0) ----------------
__global__ __launch_bounds__(256) void padzero_k(unsigned short* kpb, unsigned short* vpt) {
    int i = blockIdx.x * 256 + threadIdx.x;   // ushort4 index
    ushort4 z = {0, 0, 0, 0};
    if (i < 49152) {                 // kp pads: 128 b x 12 rows x 128
        int q = i * 4;
        int b = q / 1536, off = q - b * 1536;
        *(ushort4*)(kpb + ((size_t)b * 208 + 196) * 128 + off) = z;
    } else {                          // vpT pads: per (b,d) cols 196..223 (28 ushorts = 7 x ushort4)
        int c = i - 49152;            // 0..114687
        int bd = c / 7, cc = c - bd * 7;
        *(ushort4*)(vpt + (size_t)bd * 224 + 196 + cc * 4) = z;
    }
}

// ---------------- K1: one-pass LayerNorm(features) -> bf16 ----------------
__global__ __launch_bounds__(256) void ln_bf16_k(const float* __restrict__ f,
                                                 const float* __restrict__ g,
                                                 const float* __restrict__ bv,
                                                 unsigned short* __restrict__ out) {
    int wid = blockIdx.x * 4 + (threadIdx.x >> 6);   // one wave per row
    int lane = threadIdx.x & 63;
    const float* row = f + (size_t)wid * E_;
    float4 x[3];
    float s = 0.f, s2 = 0.f;
    #pragma unroll
    for (int c = 0; c < 3; ++c) {
        x[c] = *(const float4*)(row + c * 256 + lane * 4);
        s  += x[c].x + x[c].y + x[c].z + x[c].w;
        s2 += x[c].x * x[c].x + x[c].y * x[c].y + x[c].z * x[c].z + x[c].w * x[c].w;
    }
    s  = wave_red_sum64(s);
    s2 = wave_red_sum64(s2);
    float m = s * (1.f / E_);
    float rs = rsqrtf(s2 * (1.f / E_) - m * m + 1e-5f);
    #pragma unroll
    for (int c = 0; c < 3; ++c) {
        float4 g4 = *(const float4*)(g + c * 256 + lane * 4);
        float4 b4 = *(const float4*)(bv + c * 256 + lane * 4);
        ushort4 o;
        o.x = f2bf((x[c].x - m) * rs * g4.x + b4.x);
        o.y = f2bf((x[c].y - m) * rs * g4.y + b4.y);
        o.z = f2bf((x[c].z - m) * rs * g4.z + b4.z);
        o.w = f2bf((x[c].w - m) * rs * g4.w + b4.w);
        *(ushort4*)(out + (size_t)wid * E_ + c * 256 + lane * 4) = o;
    }
}

// ---------------- K2: bf16 MFMA GEMM -> kp_bf (y=0) / vpT_bf (y=1) directly ----------------
__global__ __launch_bounds__(256) void mfma_proj_k(const unsigned short* __restrict__ Abf,
                                                   const unsigned short* __restrict__ Wb,
                                                   unsigned short* __restrict__ kp_bf,
                                                   unsigned short* __restrict__ vpT_bf) {
    __shared__ __align__(16) unsigned short As[128 * 64];
    __shared__ __align__(16) unsigned short Bs[128 * 64];
    const int t = threadIdx.x, w = t >> 6, l = t & 63;
    const int m0 = blockIdx.x * 128;
    const int n0 = blockIdx.y * 128;
    const int wr = w >> 1, wc = w & 1;
    const int fr = l & 15, kq = l >> 4;
    f32x4 acc[4][4];
    #pragma unroll
    for (int mi = 0; mi < 4; ++mi)
        #pragma unroll
        for (int nj = 0; nj < 4; ++nj) acc[mi][nj] = (f32x4){0.f, 0.f, 0.f, 0.f};

    const int ci_l = l;
    for (int ks = 0; ks < E_; ks += 64) {
        __syncthreads();
        #pragma unroll
        for (int j = 0; j < 4; ++j) {
            int ci = (w << 8) + (j << 6) + ci_l;
            int r = ci >> 3, c = ci & 7;
            int cg = c ^ (r & 7);
            const unsigned short* ga = Abf + (size_t)(m0 + r) * E_ + ks + cg * 8;
            const unsigned short* gb = Wb  + (size_t)(n0 + r) * E_ + ks + cg * 8;
            gl_lds16(ga, As + (size_t)((w << 8) + (j << 6)) * 8);
            gl_lds16(gb, Bs + (size_t)((w << 8) + (j << 6)) * 8);
        }
        __syncthreads();
        #pragma unroll
        for (int kk = 0; kk < 2; ++kk) {
            bf16x8 af[4], bfr[4];
            int kci = kk * 4 + kq;
            int ch = kci ^ (fr & 7);
            #pragma unroll
            for (int mi = 0; mi < 4; ++mi)
                af[mi] = *(const bf16x8*)(As + (wr * 64 + mi * 16 + fr) * 64 + ch * 8);
            #pragma unroll
            for (int nj = 0; nj < 4; ++nj)
                bfr[nj] = *(const bf16x8*)(Bs + (wc * 64 + nj * 16 + fr) * 64 + ch * 8);
            #pragma unroll
            for (int mi = 0; mi < 4; ++mi)
                #pragma unroll
                for (int nj = 0; nj < 4; ++nj)
                    acc[mi][nj] = MFMA16(af[mi], bfr[nj], acc[mi][nj]);
        }
    }
    // epilogue: bf16 scatter into padded per-batch layouts
    if (blockIdx.y == 0) {
        #pragma unroll
        for (int mi = 0; mi < 4; ++mi) {
            int rowbase = m0 + wr * 64 + mi * 16 + kq * 4;
            #pragma unroll
            for (int r = 0; r < 4; ++r) {
                int m = rowbase + r;
                int b = m / 196, rr = m - b * 196;
                size_t o = ((size_t)b * 208 + rr) * 128;
                #pragma unroll
                for (int nj = 0; nj < 4; ++nj)
                    kp_bf[o + wc * 64 + nj * 16 + fr] = f2bf(acc[mi][nj][r]);
            }
        }
    } else {
        #pragma unroll
        for (int mi = 0; mi < 4; ++mi) {
            int rowbase = m0 + wr * 64 + mi * 16 + kq * 4;
            #pragma unroll
            for (int r = 0; r < 4; ++r) {
                int m = rowbase + r;
                int b = m / 196, rr = m - b * 196;
                #pragma unroll
                for (int nj = 0; nj < 4; ++nj) {
                    int col = wc * 64 + nj * 16 + fr;
                    vpT_bf[((size_t)b * 128 + col) * 224 + rr] = f2bf(acc[mi][nj][r]);
                }
            }
        }
    }
}

// ---------------- K3: persistent per-batch slot-attention iterations (MFMA) ----------------
__global__ __launch_bounds__(512) void slot_iter_mfma(
    const float* __restrict__ noise,
    const float* __restrict__ lsg, const float* __restrict__ lsb,
    const float* __restrict__ log_, const float* __restrict__ lob,
    const float* __restrict__ mup, const float* __restrict__ lsig,
    const unsigned short* __restrict__ Wq_bf,
    const unsigned short* __restrict__ Wih_bf,
    const unsigned short* __restrict__ Whh_bf,
    const float* __restrict__ bih, const float* __restrict__ bhh,
    const unsigned short* __restrict__ W1_bf, const float* __restrict__ mb1,
    const unsigned short* __restrict__ W2_bf, const float* __restrict__ mb2,
    const unsigned short* __restrict__ kp_bf,
    const unsigned short* __restrict__ vpT_bf,
    float* __restrict__ out_slots, float* __restrict__ out_attn) {

    __shared__ float slots[8][128];
    __shared__ float attn[208][9];
    __shared__ float colsum[8];
    __shared__ __align__(16) unsigned short sln_bf[2048];
    __shared__ __align__(16) unsigned short q_bf[2048];
    __shared__ __align__(16) unsigned short upd_bf[2048];
    __shared__ __align__(16) unsigned short slots_bf[2048];
    __shared__ __align__(16) unsigned short h_bf[2048];
    __shared__ __align__(16) unsigned short attnT_bf[4096];

    const int b = blockIdx.x, t = threadIdx.x;
    const int lane = t & 63, w = t >> 6;
    const int fr = lane & 15, kq = lane >> 4;

    // zero bf16 tiles once: rows 8-15 stay 0 forever; attnT pad cols stay 0
    for (int i = t; i < 2048; i += 512) {
        sln_bf[i] = 0; q_bf[i] = 0; upd_bf[i] = 0; slots_bf[i] = 0; h_bf[i] = 0;
    }
    for (int i = t; i < 4096; i += 512) attnT_bf[i] = 0;

    for (int idx = t; idx < 1024; idx += 512) {
        int k = idx >> 7, d = idx & 127;
        float v = noise[(size_t)b * 1024 + idx] * expf(lsig[d]) + mup[d];
        slots[k][d] = v;
        slots_bf[swz128(k, d)] = f2bf(v);
    }
    __syncthreads();

    for (int it = 0; it < ITERS; ++it) {
        bool last = (it == ITERS - 1);
        // (a) LN_slot -> sln_bf (wave w owns slot w)
        {
            float x0 = slots[w][lane], x1 = slots[w][lane + 64];
            float s  = wave_red_sum64(x0 + x1);
            float s2 = wave_red_sum64(x0 * x0 + x1 * x1);
            float m = s * 0.0078125f;
            float rs = rsqrtf(s2 * 0.0078125f - m * m + 1e-5f);
            sln_bf[swz128(w, lane)]      = f2bf((x0 - m) * rs * lsg[lane]      + lsb[lane]);
            sln_bf[swz128(w, lane + 64)] = f2bf((x1 - m) * rs * lsg[lane + 64] + lsb[lane + 64]);
        }
        __syncthreads();
        // (b) q = sln @ Wq^T -> q_bf (wave w owns dout tile w*16)
        {
            f32x4 acc = {0.f, 0.f, 0.f, 0.f};
            #pragma unroll
            for (int ks = 0; ks < 4; ++ks)
                acc = MFMA16(ldA128(sln_bf, fr, kq, ks), ldW128(Wq_bf, w * 16 + fr, ks, kq), acc);
            if (kq < 2) {
                #pragma unroll
                for (int r = 0; r < 4; ++r)
                    q_bf[swz128(kq * 4 + r, w * 16 + fr)] = f2bf(acc[r]);
            }
        }
        __syncthreads();
        // (c) logits tiles + softmax over slots -> attn (wave w: token tiles w, w+8)
        #pragma unroll
        for (int p = 0; p < 2; ++p) {
            int tt = w + p * 8;
            if (tt <= 12) {
                f32x4 acc = {0.f, 0.f, 0.f, 0.f};
                const unsigned short* kpr = kp_bf + ((size_t)b * 208 + tt * 16 + fr) * 128;
                #pragma unroll
                for (int ks = 0; ks < 4; ++ks)
                    acc = MFMA16(*(const bf16x8*)(kpr + ks * 32 + kq * 8),
                                 ldA128(q_bf, fr, kq, ks), acc);
                #pragma unroll
                for (int r = 0; r < 4; ++r) {
                    float v = acc[r];
                    float mx = fmaxf(v, __shfl_xor(v, 1));
                    mx = fmaxf(mx, __shfl_xor(mx, 2));
                    mx = fmaxf(mx, __shfl_xor(mx, 4));
                    float e = expf(v - mx);
                    float sm = e;
                    sm += __shfl_xor(sm, 1); sm += __shfl_xor(sm, 2); sm += __shfl_xor(sm, 4);
                    int tok = tt * 16 + kq * 4 + r;
                    if (fr < 8 && tok < 196) attn[tok][fr] = e / sm;
                }
            }
        }
        __syncthreads();
        // (d) column sums over tokens (wave w owns slot w)
        {
            float s = 0.f;
            for (int n = lane; n < 196; n += 64) s += attn[n][w];
            s = wave_red_sum64(s);
            if (lane == 0) colsum[w] = s + 196.0f * 1e-8f;
        }
        __syncthreads();
        // (e) normalize over tokens -> attnT_bf (+ out_attn on last iter)
        for (int idx = t; idx < 1568; idx += 512) {
            int n = idx >> 3, k = idx & 7;
            float raw = attn[n][k];
            attnT_bf[swz256(k, n)] = f2bf((raw + 1e-8f) / colsum[k]);
            if (last) out_attn[((size_t)b * 196 + n) * 8 + k] = raw;
        }
        __syncthreads();
        // (f) updates = attn_norm^T @ v -> upd_bf (wave w owns d tile w*16)
        {
            f32x4 acc = {0.f, 0.f, 0.f, 0.f};
            const unsigned short* vpr = vpT_bf + ((size_t)b * 128 + w * 16 + fr) * 224;
            #pragma unroll
            for (int ks = 0; ks < 7; ++ks)
                acc = MFMA16(ldA256(attnT_bf, fr, kq, ks),
                             *(const bf16x8*)(vpr + ks * 32 + kq * 8), acc);
            if (kq < 2) {
                #pragma unroll
                for (int r = 0; r < 4; ++r)
                    upd_bf[swz128(kq * 4 + r, w * 16 + fr)] = f2bf(acc[r]);
            }
        }
        __syncthreads();
        // (g) GRU: 6 MFMA tiles per wave, then gates in-register
        {
            f32x4 gi0 = {0,0,0,0}, gi1 = {0,0,0,0}, gi2 = {0,0,0,0};
            f32x4 gh0 = {0,0,0,0}, gh1 = {0,0,0,0}, gh2 = {0,0,0,0};
            #pragma unroll
            for (int ks = 0; ks < 4; ++ks) {
                bf16x8 au = ldA128(upd_bf,   fr, kq, ks);
                bf16x8 as = ldA128(slots_bf, fr, kq, ks);
                gi0 = MFMA16(au, ldW128(Wih_bf,       w * 16 + fr, ks, kq), gi0);
                gi1 = MFMA16(au, ldW128(Wih_bf, 128 + w * 16 + fr, ks, kq), gi1);
                gi2 = MFMA16(au, ldW128(Wih_bf, 256 + w * 16 + fr, ks, kq), gi2);
                gh0 = MFMA16(as, ldW128(Whh_bf,       w * 16 + fr, ks, kq), gh0);
                gh1 = MFMA16(as, ldW128(Whh_bf, 128 + w * 16 + fr, ks, kq), gh1);
                gh2 = MFMA16(as, ldW128(Whh_bf, 256 + w * 16 + fr, ks, kq), gh2);
            }
            __syncthreads();   // all slots_bf reads complete before writes below
            if (kq < 2) {
                int d = w * 16 + fr;
                float bi0 = bih[d], bi1 = bih[128 + d], bi2 = bih[256 + d];
                float bh0 = bhh[d], bh1 = bhh[128 + d], bh2 = bhh[256 + d];
                #pragma unroll
                for (int r = 0; r < 4; ++r) {
                    int m = kq * 4 + r;
                    float rr = 1.f / (1.f + expf(-((gi0[r] + bi0) + (gh0[r] + bh0))));
                    float zz = 1.f / (1.f + expf(-((gi1[r] + bi1) + (gh1[r] + bh1))));
                    float nn = tanhf((gi2[r] + bi2) + rr * (gh2[r] + bh2));
                    float h = slots[m][d];
                    float v = (1.f - zz) * nn + zz * h;
                    slots[m][d] = v;
                    slots_bf[swz128(m, d)] = f2bf(v);
                }
            }
        }
        __syncthreads();
        // (h) LN_out -> sln_bf
        {
            float x0 = slots[w][lane], x1 = slots[w][lane + 64];
            float s  = wave_red_sum64(x0 + x1);
            float s2 = wave_red_sum64(x0 * x0 + x1 * x1);
            float m = s * 0.0078125f;
            float rs = rsqrtf(s2 * 0.0078125f - m * m + 1e-5f);
            sln_bf[swz128(w, lane)]      = f2bf((x0 - m) * rs * log_[lane]      + lob[lane]);
            sln_bf[swz128(w, lane + 64)] = f2bf((x1 - m) * rs * log_[lane + 64] + lob[lane + 64]);
        }
        __syncthreads();
        // (i) MLP1 -> h_bf
        {
            f32x4 acc = {0.f, 0.f, 0.f, 0.f};
            #pragma unroll
            for (int ks = 0; ks < 4; ++ks)
                acc = MFMA16(ldA128(sln_bf, fr, kq, ks), ldW128(W1_bf, w * 16 + fr, ks, kq), acc);
            if (kq < 2) {
                float b1 = mb1[w * 16 + fr];
                #pragma unroll
                for (int r = 0; r < 4; ++r)
                    h_bf[swz128(kq * 4 + r, w * 16 + fr)] = f2bf(fmaxf(acc[r] + b1, 0.f));
            }
        }
        __syncthreads();
        // (j) MLP2 residual -> slots
        {
            f32x4 acc = {0.f, 0.f, 0.f, 0.f};
            #pragma unroll
            for (int ks = 0; ks < 4; ++ks)
                acc = MFMA16(ldA128(h_bf, fr, kq, ks), ldW128(W2_bf, w * 16 + fr, ks, kq), acc);
            if (kq < 2) {
                float b2 = mb2[w * 16 + fr];
                #pragma unroll
                for (int r = 0; r < 4; ++r) {
                    int m = kq * 4 + r, d = w * 16 + fr;
                    float v = slots[m][d] + acc[r] + b2;
                    slots[m][d] = v;
                    slots_bf[swz128(m, d)] = f2bf(v);
                }
            }
        }
        __syncthreads();
    }
    for (int idx = t; idx < 1024; idx += 512)
        out_slots[(size_t)b * 1024 + idx] = slots[idx >> 7][idx & 127];
}

// ---------------- K4: decoder MLP per batch (fp32, unchanged) ----------------
__global__ __launch_bounds__(512) void decoder_k(
    const float* __restrict__ ldg_, const float* __restrict__ ldb,
    const float* __restrict__ dW1T, const float* __restrict__ db1,
    const float* __restrict__ dW2T, const float* __restrict__ db2,
    const float* __restrict__ dW3T, const float* __restrict__ db3,
    const float* __restrict__ slots_in, float* __restrict__ sf) {

    __shared__ float s[8][128];
    __shared__ float h1[8][256];
    __shared__ float h2[8][768];
    __shared__ float part[2][8][256];
    int b = blockIdx.x, half = blockIdx.y, t = threadIdx.x;
    int lane = t & 63, w = t >> 6;

    {
        float x0 = slots_in[(size_t)b * 1024 + w * 128 + lane];
        float x1 = slots_in[(size_t)b * 1024 + w * 128 + lane + 64];
        float su  = wave_red_sum64(x0 + x1);
        float su2 = wave_red_sum64(x0 * x0 + x1 * x1);
        float m = su * (1.f / 128.f);
        float var = su2 * (1.f / 128.f) - m * m;
        float rs = rsqrtf(var + 1e-5f);
        s[w][lane]      = (x0 - m) * rs * ldg_[lane]      + ldb[lane];
        s[w][lane + 64] = (x1 - m) * rs * ldg_[lane + 64] + ldb[lane + 64];
    }
    __syncthreads();
    {
        int dout = t & 255, jc = t >> 8;
        float a[8] = {0.f,0.f,0.f,0.f,0.f,0.f,0.f,0.f};
        int j0 = jc * 64;
        #pragma unroll 4
        for (int j = j0; j < j0 + 64; ++j) {
            float wv = dW1T[j * 256 + dout];
            #pragma unroll
            for (int k = 0; k < 8; ++k) a[k] += s[k][j] * wv;
        }
        #pragma unroll
        for (int k = 0; k < 8; ++k) part[jc][k][dout] = a[k];
    }
    __syncthreads();
    for (int idx = t; idx < 2048; idx += 512) {
        int k = idx >> 8, d = idx & 255;
        h1[k][d] = fmaxf(part[0][k][d] + part[1][k][d] + db1[d], 0.f);
    }
    __syncthreads();
    for (int dout = t; dout < 768; dout += 512) {
        float a[8] = {0.f,0.f,0.f,0.f,0.f,0.f,0.f,0.f};
        #pragma unroll 4
        for (int j = 0; j < 256; ++j) {
            float wv = dW2T[j * 768 + dout];
            #pragma unroll
            for (int k = 0; k < 8; ++k) a[k] += h1[k][j] * wv;
        }
        #pragma unroll
        for (int k = 0; k < 8; ++k) h2[k][dout] = fmaxf(a[k] + db2[dout], 0.f);
    }
    __syncthreads();
    if (t < 384) {
        int dout = half * 384 + t;
        float a[8] = {0.f,0.f,0.f,0.f,0.f,0.f,0.f,0.f};
        #pragma unroll 4
        for (int j = 0; j < 768; ++j) {
            float wv = dW3T[j * 768 + dout];
            #pragma unroll
            for (int k = 0; k < 8; ++k) a[k] += h2[k][j] * wv;
        }
        #pragma unroll
        for (int k = 0; k < 8; ++k)
            sf[((size_t)b * 8 + k) * 768 + dout] = a[k] + db3[dout];
    }
}

// ---------------- K5: fused recon + squared-error partial sums ----------------
__global__ __launch_bounds__(256) void recon_loss_k(
    const float* __restrict__ feats, const float* __restrict__ attnv,
    const float* __restrict__ sf, float* __restrict__ partials) {

    __shared__ float sfl[8][768];
    __shared__ float al[49][8];
    __shared__ float wred[4];
    int b = blockIdx.x, qd = blockIdx.y, t = threadIdx.x;
    for (int idx = t; idx < 8 * 768; idx += 256)
        ((float*)sfl)[idx] = sf[(size_t)b * 8 * 768 + idx];
    int n0 = qd * 49;
    for (int idx = t; idx < 49 * 8; idx += 256)
        ((float*)al)[idx] = attnv[((size_t)b * N_ + n0) * 8 + idx];
    __syncthreads();
    float acc = 0.f;
    for (int nl = 0; nl < 49; ++nl) {
        float a0 = al[nl][0], a1 = al[nl][1], a2 = al[nl][2], a3 = al[nl][3];
        float a4 = al[nl][4], a5 = al[nl][5], a6 = al[nl][6], a7 = al[nl][7];
        const float* frow = feats + ((size_t)(b * N_ + n0 + nl)) * E_;
        for (int c = t; c < E_; c += 256) {
            float r = sfl[0][c]*a0 + sfl[1][c]*a1 + sfl[2][c]*a2 + sfl[3][c]*a3
                    + sfl[4][c]*a4 + sfl[5][c]*a5 + sfl[6][c]*a6 + sfl[7][c]*a7;
            float d = r - frow[c];
            acc += d * d;
        }
    }
    acc = wave_red_sum64(acc);
    int lane = t & 63, w = t >> 6;
    if (lane == 0) wred[w] = acc;
    __syncthreads();
    if (t == 0) partials[b * 4 + qd] = wred[0] + wred[1] + wred[2] + wred[3];
}

__global__ __launch_bounds__(512) void loss_final_k(const float* __restrict__ partials,
                                                    float* __restrict__ out) {
    __shared__ float wred[8];
    int t = threadIdx.x;
    float v = partials[t];
    v = wave_red_sum64(v);
    if ((t & 63) == 0) wred[t >> 6] = v;
    __syncthreads();
    if (t == 0) {
        float s = 0.f;
        #pragma unroll
        for (int i = 0; i < 8; ++i) s += wred[i];
        out[0] = s / (float)(B_ * N_ * E_);
    }
}

// ---------------- launch ----------------
extern "C" void kernel_launch(void* const* d_in, const int* in_sizes, int n_in,
                              void* d_out, int out_size, void* d_ws, size_t ws_size,
                              hipStream_t stream) {
    (void)in_sizes; (void)n_in; (void)out_size; (void)ws_size;
    const float* feats     = (const float*)d_in[0];
    const float* noise     = (const float*)d_in[1];
    const float* ln_in_g   = (const float*)d_in[2];
    const float* ln_in_b   = (const float*)d_in[3];
    const float* ln_slot_g = (const float*)d_in[4];
    const float* ln_slot_b = (const float*)d_in[5];
    const float* ln_out_g  = (const float*)d_in[6];
    const float* ln_out_b  = (const float*)d_in[7];
    const float* ln_dec_g  = (const float*)d_in[8];
    const float* ln_dec_b  = (const float*)d_in[9];
    const float* mu        = (const float*)d_in[10];
    const float* log_sigma = (const float*)d_in[11];
    const float* Wk        = (const float*)d_in[12];
    const float* Wq        = (const float*)d_in[13];
    const float* Wv        = (const float*)d_in[14];
    const float* W_ih      = (const float*)d_in[15];
    const float* W_hh      = (const float*)d_in[16];
    const float* b_ih      = (const float*)d_in[17];
    const float* b_hh      = (const float*)d_in[18];
    const float* mlp_W1    = (const float*)d_in[19];
    const float* mlp_b1    = (const float*)d_in[20];
    const float* mlp_W2    = (const float*)d_in[21];
    const float* mlp_b2    = (const float*)d_in[22];
    const float* dec_W1    = (const float*)d_in[23];
    const float* dec_b1    = (const float*)d_in[24];
    const float* dec_W2    = (const float*)d_in[25];
    const float* dec_b2    = (const float*)d_in[26];
    const float* dec_W3    = (const float*)d_in[27];
    const float* dec_b3    = (const float*)d_in[28];

    float* ws    = (float*)d_ws;
    float* sf    = ws + OFF_SF;
    float* parts = ws + OFF_PART;
    float* dW1T  = ws + OFF_DW1T;
    float* dW2T  = ws + OFF_DW2T;
    float* dW3T  = ws + OFF_DW3T;
    unsigned short* Wb     = (unsigned short*)(ws + OFF_WBF);  // Wk|Wv bf16 [256][768]
    unsigned short* Wq_bf  = Wb + 196608;
    unsigned short* Wih_bf = Wb + 212992;
    unsigned short* Whh_bf = Wb + 262144;
    unsigned short* W1_bf  = Wb + 311296;
    unsigned short* W2_bf  = Wb + 327680;
    unsigned short* kp_bf  = (unsigned short*)(ws + OFF_KPBF);   // [128][208][128]
    unsigned short* vpT_bf = (unsigned short*)(ws + OFF_VPTBF);  // [128][128][224]
    unsigned short* Abf    = (unsigned short*)(ws + OFF_ABF);    // [25088][768]

    float* out_slots = (float*)d_out;               // [128,8,128]
    float* out_attn  = out_slots + 131072;          // [128,196,8]
    float* out_loss  = out_slots + 331776;          // scalar

    // decoder fp32 transposes: tiles {32, 192, 576} -> t0 {0, 32, 224}, total 800
    T3Args ta;
    ta.m[0] = {dec_W1, dW1T, 256, 128, 0};
    ta.m[1] = {dec_W2, dW2T, 768, 256, 32};
    ta.m[2] = {dec_W3, dW3T, 768, 768, 224};
    tAll<<<800, dim3(32, 8), 0, stream>>>(ta);

    // bf16 weight conversions (2048 elems per block)
    WCArgs wa;
    wa.m[0] = {Wk,     Wb,               0.08838834764831845f, 0};    // 48 blocks
    wa.m[1] = {Wv,     Wb + 98304,       1.f,                  48};   // 48
    wa.m[2] = {Wq,     Wq_bf,            1.f,                  96};   // 8
    wa.m[3] = {W_ih,   Wih_bf,           1.f,                  104};  // 24
    wa.m[4] = {W_hh,   Whh_bf,           1.f,                  128};  // 24
    wa.m[5] = {mlp_W1, W1_bf,            1.f,                  152};  // 8
    wa.m[6] = {mlp_W2, W2_bf,            1.f,                  160};  // 8 -> total 168
    wconv_all<<<168, 256, 0, stream>>>(wa);

    padzero_k<<<640, 256, 0, stream>>>(kp_bf, vpT_bf);
    ln_bf16_k<<<BNR / 4, 256, 0, stream>>>(feats, ln_in_g, ln_in_b, Abf);
    mfma_proj_k<<<dim3(BNR / 128, 2), 256, 0, stream>>>(Abf, Wb, kp_bf, vpT_bf);

    slot_iter_mfma<<<B_, 512, 0, stream>>>(noise, ln_slot_g, ln_slot_b, ln_out_g, ln_out_b,
                                           mu, log_sigma, Wq_bf, Wih_bf, Whh_bf, b_ih, b_hh,
                                           W1_bf, mlp_b1, W2_bf, mlp_b2, kp_bf, vpT_bf,
                                           out_slots, out_attn);
    decoder_k<<<dim3(B_, 2), 512, 0, stream>>>(ln_dec_g, ln_dec_b, dW1T, dec_b1,
                                               dW2T, dec_b2, dW3T, dec_b3,
                                               out_slots, sf);
    recon_loss_k<<<dim3(B_, 4), 256, 0, stream>>>(feats, out_attn, sf, parts);
    loss_final_k<<<1, 512, 0, stream>>>(parts, out_loss);
}

// Round 5
// 202.479 us; speedup vs baseline: 2.5178x; 1.4452x over previous
//
#include <hip/hip_runtime.h>
#include <hip/hip_bf16.h>
#include <math.h>

// ---------------- problem constants ----------------
#define B_    128
#define N_    196
#define E_    768
#define K_    8
#define D_    128
#define BNR   (B_*N_)        // 25088 rows
#define ITERS 5

// ws layout (float units)
#define OFF_PART   0          // 512
#define OFF_SDEC   512        // ushort[1024*128] = 65536 floats
#define OFF_WBF    66048      // ushort region: 1163264 ushorts = 581632 floats
#define OFF_KPBF   647680     // ushort[128*208*128] = 1703936 floats
#define OFF_VPTBF  2351616    // ushort[128*128*224] = 1835008 floats
#define OFF_ABF    4186624    // ushort[25088*768] = 9633792 floats (aliased after proj)

typedef __attribute__((ext_vector_type(8))) short bf16x8;
typedef __attribute__((ext_vector_type(4))) float f32x4;

#define MFMA16(a, b, c) __builtin_amdgcn_mfma_f32_16x16x32_bf16(a, b, c, 0, 0, 0)

__device__ __forceinline__ float wave_red_sum64(float v) {
    #pragma unroll
    for (int o = 32; o > 0; o >>= 1) v += __shfl_xor(v, o);
    return v;
}

__device__ __forceinline__ unsigned short f2bf(float v) {
    union { float f; unsigned int u; } c; c.f = v;
    unsigned int u = c.u + 0x7fffu + ((c.u >> 16) & 1u);  // RNE
    return (unsigned short)(u >> 16);
}

__device__ __forceinline__ void gl_lds16(const void* g, void* l) {
    __builtin_amdgcn_global_load_lds(
        (const __attribute__((address_space(1))) unsigned int*)g,
        (__attribute__((address_space(3))) unsigned int*)l, 16, 0, 0);
}

// chunk-XOR swizzled LDS addressing (8-bf16 = 16B chunks; XOR low 3 chunk bits with row&7)
__device__ __forceinline__ int swz128(int row, int j) {
    return row * 128 + ((((j >> 3) ^ (row & 7))) << 3) + (j & 7);
}
__device__ __forceinline__ int swz256(int row, int j) {
    return row * 256 + ((((j >> 3) ^ (row & 7))) << 3) + (j & 7);
}
__device__ __forceinline__ bf16x8 ldA128(const unsigned short* base, int fr, int kq, int ks) {
    int ch = (ks * 4 + kq) ^ (fr & 7);
    return *(const bf16x8*)(base + fr * 128 + ch * 8);
}
__device__ __forceinline__ bf16x8 ldA256(const unsigned short* base, int fr, int kq, int ks) {
    int ch = (ks * 4 + kq) ^ (fr & 7);
    return *(const bf16x8*)(base + fr * 256 + ch * 8);
}
__device__ __forceinline__ bf16x8 ldW128(const unsigned short* W, int row, int ks, int kq) {
    return *(const bf16x8*)(W + (size_t)row * 128 + ks * 32 + kq * 8);
}

// ---------------- K0b: all weights -> bf16 (row-major, kscale folded into Wk) ----------------
struct WCEnt { const float* s; unsigned short* d; float scale; int t0; };
struct WCArgs { WCEnt m[10]; };

__global__ __launch_bounds__(256) void wconv_all(WCArgs a) {
    int bid = blockIdx.x, i = 0;
    #pragma unroll
    for (int j = 1; j < 10; ++j) if (bid >= a.m[j].t0) i = j;
    int off = (bid - a.m[i].t0) * 2048 + threadIdx.x * 8;
    const float* s = a.m[i].s + off;
    unsigned short* d = a.m[i].d + off;
    float sc = a.m[i].scale;
    float4 v0 = *(const float4*)s, v1 = *(const float4*)(s + 4);
    ushort4 o0, o1;
    o0.x = f2bf(v0.x * sc); o0.y = f2bf(v0.y * sc);
    o0.z = f2bf(v0.z * sc); o0.w = f2bf(v0.w * sc);
    o1.x = f2bf(v1.x * sc); o1.y = f2bf(v1.y * sc);
    o1.z = f2bf(v1.z * sc); o1.w = f2bf(v1.w * sc);
    *(ushort4*)d = o0; *(ushort4*)(d + 4) = o1;
}

// ---------------- K0c: zero the kp_bf / vpT_bf padding ----------------
__global__ __launch_bounds__(256) void padzero_k(unsigned short* kpb, unsigned short* vpt) {
    int i = blockIdx.x * 256 + threadIdx.x;   // ushort4 index
    ushort4 z = {0, 0, 0, 0};
    if (i < 49152) {                 // kp pads: 128 b x 12 rows x 128
        int q = i * 4;
        int b = q / 1536, off = q - b * 1536;
        *(ushort4*)(kpb + ((size_t)b * 208 + 196) * 128 + off) = z;
    } else {                          // vpT pads: per (b,d) cols 196..223
        int c = i - 49152;            // 0..114687
        int bd = c / 7, cc = c - bd * 7;
        *(ushort4*)(vpt + (size_t)bd * 224 + 196 + cc * 4) = z;
    }
}

// ---------------- K1: one-pass LayerNorm(features) -> bf16 ----------------
__global__ __launch_bounds__(256) void ln_bf16_k(const float* __restrict__ f,
                                                 const float* __restrict__ g,
                                                 const float* __restrict__ bv,
                                                 unsigned short* __restrict__ out) {
    int wid = blockIdx.x * 4 + (threadIdx.x >> 6);   // one wave per row
    int lane = threadIdx.x & 63;
    const float* row = f + (size_t)wid * E_;
    float4 x[3];
    float s = 0.f, s2 = 0.f;
    #pragma unroll
    for (int c = 0; c < 3; ++c) {
        x[c] = *(const float4*)(row + c * 256 + lane * 4);
        s  += x[c].x + x[c].y + x[c].z + x[c].w;
        s2 += x[c].x * x[c].x + x[c].y * x[c].y + x[c].z * x[c].z + x[c].w * x[c].w;
    }
    s  = wave_red_sum64(s);
    s2 = wave_red_sum64(s2);
    float m = s * (1.f / E_);
    float rs = rsqrtf(s2 * (1.f / E_) - m * m + 1e-5f);
    #pragma unroll
    for (int c = 0; c < 3; ++c) {
        float4 g4 = *(const float4*)(g + c * 256 + lane * 4);
        float4 b4 = *(const float4*)(bv + c * 256 + lane * 4);
        ushort4 o;
        o.x = f2bf((x[c].x - m) * rs * g4.x + b4.x);
        o.y = f2bf((x[c].y - m) * rs * g4.y + b4.y);
        o.z = f2bf((x[c].z - m) * rs * g4.z + b4.z);
        o.w = f2bf((x[c].w - m) * rs * g4.w + b4.w);
        *(ushort4*)(out + (size_t)wid * E_ + c * 256 + lane * 4) = o;
    }
}

// ---------------- K2: bf16 MFMA GEMM -> kp_bf (y=0) / vpT_bf (y=1) ----------------
__global__ __launch_bounds__(256) void mfma_proj_k(const unsigned short* __restrict__ Abf,
                                                   const unsigned short* __restrict__ Wb,
                                                   unsigned short* __restrict__ kp_bf,
                                                   unsigned short* __restrict__ vpT_bf) {
    __shared__ __align__(16) unsigned short As[128 * 64];
    __shared__ __align__(16) unsigned short Bs[128 * 64];
    const int t = threadIdx.x, w = t >> 6, l = t & 63;
    const int m0 = blockIdx.x * 128;
    const int n0 = blockIdx.y * 128;
    const int wr = w >> 1, wc = w & 1;
    const int fr = l & 15, kq = l >> 4;
    f32x4 acc[4][4];
    #pragma unroll
    for (int mi = 0; mi < 4; ++mi)
        #pragma unroll
        for (int nj = 0; nj < 4; ++nj) acc[mi][nj] = (f32x4){0.f, 0.f, 0.f, 0.f};

    for (int ks = 0; ks < E_; ks += 64) {
        __syncthreads();
        #pragma unroll
        for (int j = 0; j < 4; ++j) {
            int ci = (w << 8) + (j << 6) + l;
            int r = ci >> 3, c = ci & 7;
            int cg = c ^ (r & 7);
            const unsigned short* ga = Abf + (size_t)(m0 + r) * E_ + ks + cg * 8;
            const unsigned short* gb = Wb  + (size_t)(n0 + r) * E_ + ks + cg * 8;
            gl_lds16(ga, As + (size_t)((w << 8) + (j << 6)) * 8);
            gl_lds16(gb, Bs + (size_t)((w << 8) + (j << 6)) * 8);
        }
        __syncthreads();
        #pragma unroll
        for (int kk = 0; kk < 2; ++kk) {
            bf16x8 af[4], bfr[4];
            int kci = kk * 4 + kq;
            int ch = kci ^ (fr & 7);
            #pragma unroll
            for (int mi = 0; mi < 4; ++mi)
                af[mi] = *(const bf16x8*)(As + (wr * 64 + mi * 16 + fr) * 64 + ch * 8);
            #pragma unroll
            for (int nj = 0; nj < 4; ++nj)
                bfr[nj] = *(const bf16x8*)(Bs + (wc * 64 + nj * 16 + fr) * 64 + ch * 8);
            #pragma unroll
            for (int mi = 0; mi < 4; ++mi)
                #pragma unroll
                for (int nj = 0; nj < 4; ++nj)
                    acc[mi][nj] = MFMA16(af[mi], bfr[nj], acc[mi][nj]);
        }
    }
    if (blockIdx.y == 0) {
        #pragma unroll
        for (int mi = 0; mi < 4; ++mi) {
            int rowbase = m0 + wr * 64 + mi * 16 + kq * 4;
            #pragma unroll
            for (int r = 0; r < 4; ++r) {
                int m = rowbase + r;
                int b = m / 196, rr = m - b * 196;
                size_t o = ((size_t)b * 208 + rr) * 128;
                #pragma unroll
                for (int nj = 0; nj < 4; ++nj)
                    kp_bf[o + wc * 64 + nj * 16 + fr] = f2bf(acc[mi][nj][r]);
            }
        }
    } else {
        #pragma unroll
        for (int mi = 0; mi < 4; ++mi) {
            int rowbase = m0 + wr * 64 + mi * 16 + kq * 4;
            #pragma unroll
            for (int r = 0; r < 4; ++r) {
                int m = rowbase + r;
                int b = m / 196, rr = m - b * 196;
                #pragma unroll
                for (int nj = 0; nj < 4; ++nj) {
                    int col = wc * 64 + nj * 16 + fr;
                    vpT_bf[((size_t)b * 128 + col) * 224 + rr] = f2bf(acc[mi][nj][r]);
                }
            }
        }
    }
}

// ---------------- K2b: generic MLP-layer MFMA GEMM ----------------
// A [M][KTOT] bf16, Bw [N][KTOT] bf16 (torch layout), 128x128 tile, BK=64.
// EPI 0: out_bf = bf16(relu(x+bias)); EPI 1: out_f = x+bias (fp32).
template<int KTOT, int EPI>
__global__ __launch_bounds__(256) void mfma_mlp_k(const unsigned short* __restrict__ A,
                                                  const unsigned short* __restrict__ Bw,
                                                  const float* __restrict__ bias,
                                                  unsigned short* __restrict__ out_bf,
                                                  float* __restrict__ out_f,
                                                  int ldN) {
    __shared__ __align__(16) unsigned short As[128 * 64];
    __shared__ __align__(16) unsigned short Bs[128 * 64];
    const int t = threadIdx.x, w = t >> 6, l = t & 63;
    const int m0 = blockIdx.x * 128;
    const int n0 = blockIdx.y * 128;
    const int wr = w >> 1, wc = w & 1;
    const int fr = l & 15, kq = l >> 4;
    f32x4 acc[4][4];
    #pragma unroll
    for (int mi = 0; mi < 4; ++mi)
        #pragma unroll
        for (int nj = 0; nj < 4; ++nj) acc[mi][nj] = (f32x4){0.f, 0.f, 0.f, 0.f};

    for (int ks = 0; ks < KTOT; ks += 64) {
        __syncthreads();
        #pragma unroll
        for (int j = 0; j < 4; ++j) {
            int ci = (w << 8) + (j << 6) + l;
            int r = ci >> 3, c = ci & 7;
            int cg = c ^ (r & 7);
            gl_lds16(A  + (size_t)(m0 + r) * KTOT + ks + cg * 8,
                     As + (size_t)((w << 8) + (j << 6)) * 8);
            gl_lds16(Bw + (size_t)(n0 + r) * KTOT + ks + cg * 8,
                     Bs + (size_t)((w << 8) + (j << 6)) * 8);
        }
        __syncthreads();
        #pragma unroll
        for (int kk = 0; kk < 2; ++kk) {
            bf16x8 af[4], bfr[4];
            int ch = (kk * 4 + kq) ^ (fr & 7);
            #pragma unroll
            for (int mi = 0; mi < 4; ++mi)
                af[mi] = *(const bf16x8*)(As + (wr * 64 + mi * 16 + fr) * 64 + ch * 8);
            #pragma unroll
            for (int nj = 0; nj < 4; ++nj)
                bfr[nj] = *(const bf16x8*)(Bs + (wc * 64 + nj * 16 + fr) * 64 + ch * 8);
            #pragma unroll
            for (int mi = 0; mi < 4; ++mi)
                #pragma unroll
                for (int nj = 0; nj < 4; ++nj)
                    acc[mi][nj] = MFMA16(af[mi], bfr[nj], acc[mi][nj]);
        }
    }
    #pragma unroll
    for (int mi = 0; mi < 4; ++mi) {
        int rowbase = m0 + wr * 64 + mi * 16 + kq * 4;
        #pragma unroll
        for (int nj = 0; nj < 4; ++nj) {
            int col = n0 + wc * 64 + nj * 16 + fr;
            float bc = bias[col];
            #pragma unroll
            for (int r = 0; r < 4; ++r) {
                float v = acc[mi][nj][r] + bc;
                if (EPI == 0)
                    out_bf[(size_t)(rowbase + r) * ldN + col] = f2bf(fmaxf(v, 0.f));
                else
                    out_f[(size_t)(rowbase + r) * ldN + col] = v;
            }
        }
    }
}

// ---------------- K3: persistent per-batch slot-attention iterations (MFMA) ----------------
__global__ __launch_bounds__(512) void slot_iter_mfma(
    const float* __restrict__ noise,
    const float* __restrict__ lsg, const float* __restrict__ lsb,
    const float* __restrict__ log_, const float* __restrict__ lob,
    const float* __restrict__ ldg_, const float* __restrict__ ldb_,
    const float* __restrict__ mup, const float* __restrict__ lsig,
    const unsigned short* __restrict__ Wq_bf,
    const unsigned short* __restrict__ Wih_bf,
    const unsigned short* __restrict__ Whh_bf,
    const float* __restrict__ bih, const float* __restrict__ bhh,
    const unsigned short* __restrict__ W1_bf, const float* __restrict__ mb1,
    const unsigned short* __restrict__ W2_bf, const float* __restrict__ mb2,
    const unsigned short* __restrict__ kp_bf,
    const unsigned short* __restrict__ vpT_bf,
    float* __restrict__ out_slots, float* __restrict__ out_attn,
    unsigned short* __restrict__ sdec_bf) {

    __shared__ float slots[8][128];
    __shared__ float attn[208][9];
    __shared__ float colsum[8];
    __shared__ __align__(16) unsigned short sln_bf[2048];
    __shared__ __align__(16) unsigned short q_bf[2048];
    __shared__ __align__(16) unsigned short upd_bf[2048];
    __shared__ __align__(16) unsigned short slots_bf[2048];
    __shared__ __align__(16) unsigned short h_bf[2048];
    __shared__ __align__(16) unsigned short attnT_bf[4096];

    const int b = blockIdx.x, t = threadIdx.x;
    const int lane = t & 63, w = t >> 6;
    const int fr = lane & 15, kq = lane >> 4;

    for (int i = t; i < 2048; i += 512) {
        sln_bf[i] = 0; q_bf[i] = 0; upd_bf[i] = 0; slots_bf[i] = 0; h_bf[i] = 0;
    }
    for (int i = t; i < 4096; i += 512) attnT_bf[i] = 0;

    for (int idx = t; idx < 1024; idx += 512) {
        int k = idx >> 7, d = idx & 127;
        float v = noise[(size_t)b * 1024 + idx] * expf(lsig[d]) + mup[d];
        slots[k][d] = v;
        slots_bf[swz128(k, d)] = f2bf(v);
    }
    __syncthreads();

    for (int it = 0; it < ITERS; ++it) {
        bool last = (it == ITERS - 1);
        // (a) LN_slot -> sln_bf
        {
            float x0 = slots[w][lane], x1 = slots[w][lane + 64];
            float s  = wave_red_sum64(x0 + x1);
            float s2 = wave_red_sum64(x0 * x0 + x1 * x1);
            float m = s * 0.0078125f;
            float rs = rsqrtf(s2 * 0.0078125f - m * m + 1e-5f);
            sln_bf[swz128(w, lane)]      = f2bf((x0 - m) * rs * lsg[lane]      + lsb[lane]);
            sln_bf[swz128(w, lane + 64)] = f2bf((x1 - m) * rs * lsg[lane + 64] + lsb[lane + 64]);
        }
        __syncthreads();
        // (b) q = sln @ Wq^T -> q_bf
        {
            f32x4 acc = {0.f, 0.f, 0.f, 0.f};
            #pragma unroll
            for (int ks = 0; ks < 4; ++ks)
                acc = MFMA16(ldA128(sln_bf, fr, kq, ks), ldW128(Wq_bf, w * 16 + fr, ks, kq), acc);
            if (kq < 2) {
                #pragma unroll
                for (int r = 0; r < 4; ++r)
                    q_bf[swz128(kq * 4 + r, w * 16 + fr)] = f2bf(acc[r]);
            }
        }
        __syncthreads();
        // (c) logits + softmax over slots
        #pragma unroll
        for (int p = 0; p < 2; ++p) {
            int tt = w + p * 8;
            if (tt <= 12) {
                f32x4 acc = {0.f, 0.f, 0.f, 0.f};
                const unsigned short* kpr = kp_bf + ((size_t)b * 208 + tt * 16 + fr) * 128;
                #pragma unroll
                for (int ks = 0; ks < 4; ++ks)
                    acc = MFMA16(*(const bf16x8*)(kpr + ks * 32 + kq * 8),
                                 ldA128(q_bf, fr, kq, ks), acc);
                #pragma unroll
                for (int r = 0; r < 4; ++r) {
                    float v = acc[r];
                    float mx = fmaxf(v, __shfl_xor(v, 1));
                    mx = fmaxf(mx, __shfl_xor(mx, 2));
                    mx = fmaxf(mx, __shfl_xor(mx, 4));
                    float e = expf(v - mx);
                    float sm = e;
                    sm += __shfl_xor(sm, 1); sm += __shfl_xor(sm, 2); sm += __shfl_xor(sm, 4);
                    int tok = tt * 16 + kq * 4 + r;
                    if (fr < 8 && tok < 196) attn[tok][fr] = e / sm;
                }
            }
        }
        __syncthreads();
        // (d) column sums
        {
            float s = 0.f;
            for (int n = lane; n < 196; n += 64) s += attn[n][w];
            s = wave_red_sum64(s);
            if (lane == 0) colsum[w] = s + 196.0f * 1e-8f;
        }
        __syncthreads();
        // (e) normalize -> attnT_bf (+ out_attn last iter)
        for (int idx = t; idx < 1568; idx += 512) {
            int n = idx >> 3, k = idx & 7;
            float raw = attn[n][k];
            attnT_bf[swz256(k, n)] = f2bf((raw + 1e-8f) / colsum[k]);
            if (last) out_attn[((size_t)b * 196 + n) * 8 + k] = raw;
        }
        __syncthreads();
        // (f) updates = attn_norm^T @ v
        {
            f32x4 acc = {0.f, 0.f, 0.f, 0.f};
            const unsigned short* vpr = vpT_bf + ((size_t)b * 128 + w * 16 + fr) * 224;
            #pragma unroll
            for (int ks = 0; ks < 7; ++ks)
                acc = MFMA16(ldA256(attnT_bf, fr, kq, ks),
                             *(const bf16x8*)(vpr + ks * 32 + kq * 8), acc);
            if (kq < 2) {
                #pragma unroll
                for (int r = 0; r < 4; ++r)
                    upd_bf[swz128(kq * 4 + r, w * 16 + fr)] = f2bf(acc[r]);
            }
        }
        __syncthreads();
        // (g) GRU
        {
            f32x4 gi0 = {0,0,0,0}, gi1 = {0,0,0,0}, gi2 = {0,0,0,0};
            f32x4 gh0 = {0,0,0,0}, gh1 = {0,0,0,0}, gh2 = {0,0,0,0};
            #pragma unroll
            for (int ks = 0; ks < 4; ++ks) {
                bf16x8 au = ldA128(upd_bf,   fr, kq, ks);
                bf16x8 as = ldA128(slots_bf, fr, kq, ks);
                gi0 = MFMA16(au, ldW128(Wih_bf,       w * 16 + fr, ks, kq), gi0);
                gi1 = MFMA16(au, ldW128(Wih_bf, 128 + w * 16 + fr, ks, kq), gi1);
                gi2 = MFMA16(au, ldW128(Wih_bf, 256 + w * 16 + fr, ks, kq), gi2);
                gh0 = MFMA16(as, ldW128(Whh_bf,       w * 16 + fr, ks, kq), gh0);
                gh1 = MFMA16(as, ldW128(Whh_bf, 128 + w * 16 + fr, ks, kq), gh1);
                gh2 = MFMA16(as, ldW128(Whh_bf, 256 + w * 16 + fr, ks, kq), gh2);
            }
            __syncthreads();
            if (kq < 2) {
                int d = w * 16 + fr;
                float bi0 = bih[d], bi1 = bih[128 + d], bi2 = bih[256 + d];
                float bh0 = bhh[d], bh1 = bhh[128 + d], bh2 = bhh[256 + d];
                #pragma unroll
                for (int r = 0; r < 4; ++r) {
                    int m = kq * 4 + r;
                    float rr = 1.f / (1.f + expf(-((gi0[r] + bi0) + (gh0[r] + bh0))));
                    float zz = 1.f / (1.f + expf(-((gi1[r] + bi1) + (gh1[r] + bh1))));
                    float nn = tanhf((gi2[r] + bi2) + rr * (gh2[r] + bh2));
                    float h = slots[m][d];
                    float v = (1.f - zz) * nn + zz * h;
                    slots[m][d] = v;
                    slots_bf[swz128(m, d)] = f2bf(v);
                }
            }
        }
        __syncthreads();
        // (h) LN_out -> sln_bf
        {
            float x0 = slots[w][lane], x1 = slots[w][lane + 64];
            float s  = wave_red_sum64(x0 + x1);
            float s2 = wave_red_sum64(x0 * x0 + x1 * x1);
            float m = s * 0.0078125f;
            float rs = rsqrtf(s2 * 0.0078125f - m * m + 1e-5f);
            sln_bf[swz128(w, lane)]      = f2bf((x0 - m) * rs * log_[lane]      + lob[lane]);
            sln_bf[swz128(w, lane + 64)] = f2bf((x1 - m) * rs * log_[lane + 64] + lob[lane + 64]);
        }
        __syncthreads();
        // (i) MLP1 -> h_bf
        {
            f32x4 acc = {0.f, 0.f, 0.f, 0.f};
            #pragma unroll
            for (int ks = 0; ks < 4; ++ks)
                acc = MFMA16(ldA128(sln_bf, fr, kq, ks), ldW128(W1_bf, w * 16 + fr, ks, kq), acc);
            if (kq < 2) {
                float b1 = mb1[w * 16 + fr];
                #pragma unroll
                for (int r = 0; r < 4; ++r)
                    h_bf[swz128(kq * 4 + r, w * 16 + fr)] = f2bf(fmaxf(acc[r] + b1, 0.f));
            }
        }
        __syncthreads();
        // (j) MLP2 residual -> slots
        {
            f32x4 acc = {0.f, 0.f, 0.f, 0.f};
            #pragma unroll
            for (int ks = 0; ks < 4; ++ks)
                acc = MFMA16(ldA128(h_bf, fr, kq, ks), ldW128(W2_bf, w * 16 + fr, ks, kq), acc);
            if (kq < 2) {
                float b2 = mb2[w * 16 + fr];
                #pragma unroll
                for (int r = 0; r < 4; ++r) {
                    int m = kq * 4 + r, d = w * 16 + fr;
                    float v = slots[m][d] + acc[r] + b2;
                    slots[m][d] = v;
                    slots_bf[swz128(m, d)] = f2bf(v);
                }
            }
        }
        __syncthreads();
    }
    // epilogue: raw slots out + fused LN_dec -> sdec_bf
    {
        float x0 = slots[w][lane], x1 = slots[w][lane + 64];
        out_slots[(size_t)b * 1024 + w * 128 + lane]      = x0;
        out_slots[(size_t)b * 1024 + w * 128 + lane + 64] = x1;
        float s  = wave_red_sum64(x0 + x1);
        float s2 = wave_red_sum64(x0 * x0 + x1 * x1);
        float m = s * 0.0078125f;
        float rs = rsqrtf(s2 * 0.0078125f - m * m + 1e-5f);
        sdec_bf[((size_t)b * 8 + w) * 128 + lane]      = f2bf((x0 - m) * rs * ldg_[lane]      + ldb_[lane]);
        sdec_bf[((size_t)b * 8 + w) * 128 + lane + 64] = f2bf((x1 - m) * rs * ldg_[lane + 64] + ldb_[lane + 64]);
    }
}

// ---------------- K5: fused recon + squared-error partial sums ----------------
__global__ __launch_bounds__(256) void recon_loss_k(
    const float* __restrict__ feats, const float* __restrict__ attnv,
    const float* __restrict__ sf, float* __restrict__ partials) {

    __shared__ float sfl[8][768];
    __shared__ float al[49][8];
    __shared__ float wred[4];
    int b = blockIdx.x, qd = blockIdx.y, t = threadIdx.x;
    for (int idx = t; idx < 8 * 768; idx += 256)
        ((float*)sfl)[idx] = sf[(size_t)b * 8 * 768 + idx];
    int n0 = qd * 49;
    for (int idx = t; idx < 49 * 8; idx += 256)
        ((float*)al)[idx] = attnv[((size_t)b * N_ + n0) * 8 + idx];
    __syncthreads();
    float acc = 0.f;
    for (int nl = 0; nl < 49; ++nl) {
        float a0 = al[nl][0], a1 = al[nl][1], a2 = al[nl][2], a3 = al[nl][3];
        float a4 = al[nl][4], a5 = al[nl][5], a6 = al[nl][6], a7 = al[nl][7];
        const float* frow = feats + ((size_t)(b * N_ + n0 + nl)) * E_;
        for (int c = t; c < E_; c += 256) {
            float r = sfl[0][c]*a0 + sfl[1][c]*a1 + sfl[2][c]*a2 + sfl[3][c]*a3
                    + sfl[4][c]*a4 + sfl[5][c]*a5 + sfl[6][c]*a6 + sfl[7][c]*a7;
            float d = r - frow[c];
            acc += d * d;
        }
    }
    acc = wave_red_sum64(acc);
    int lane = t & 63, w = t >> 6;
    if (lane == 0) wred[w] = acc;
    __syncthreads();
    if (t == 0) partials[b * 4 + qd] = wred[0] + wred[1] + wred[2] + wred[3];
}

__global__ __launch_bounds__(512) void loss_final_k(const float* __restrict__ partials,
                                                    float* __restrict__ out) {
    __shared__ float wred[8];
    int t = threadIdx.x;
    float v = partials[t];
    v = wave_red_sum64(v);
    if ((t & 63) == 0) wred[t >> 6] = v;
    __syncthreads();
    if (t == 0) {
        float s = 0.f;
        #pragma unroll
        for (int i = 0; i < 8; ++i) s += wred[i];
        out[0] = s / (float)(B_ * N_ * E_);
    }
}

// ---------------- launch ----------------
extern "C" void kernel_launch(void* const* d_in, const int* in_sizes, int n_in,
                              void* d_out, int out_size, void* d_ws, size_t ws_size,
                              hipStream_t stream) {
    (void)in_sizes; (void)n_in; (void)out_size; (void)ws_size;
    const float* feats     = (const float*)d_in[0];
    const float* noise     = (const float*)d_in[1];
    const float* ln_in_g   = (const float*)d_in[2];
    const float* ln_in_b   = (const float*)d_in[3];
    const float* ln_slot_g = (const float*)d_in[4];
    const float* ln_slot_b = (const float*)d_in[5];
    const float* ln_out_g  = (const float*)d_in[6];
    const float* ln_out_b  = (const float*)d_in[7];
    const float* ln_dec_g  = (const float*)d_in[8];
    const float* ln_dec_b  = (const float*)d_in[9];
    const float* mu        = (const float*)d_in[10];
    const float* log_sigma = (const float*)d_in[11];
    const float* Wk        = (const float*)d_in[12];
    const float* Wq        = (const float*)d_in[13];
    const float* Wv        = (const float*)d_in[14];
    const float* W_ih      = (const float*)d_in[15];
    const float* W_hh      = (const float*)d_in[16];
    const float* b_ih      = (const float*)d_in[17];
    const float* b_hh      = (const float*)d_in[18];
    const float* mlp_W1    = (const float*)d_in[19];
    const float* mlp_b1    = (const float*)d_in[20];
    const float* mlp_W2    = (const float*)d_in[21];
    const float* mlp_b2    = (const float*)d_in[22];
    const float* dec_W1    = (const float*)d_in[23];
    const float* dec_b1    = (const float*)d_in[24];
    const float* dec_W2    = (const float*)d_in[25];
    const float* dec_b2    = (const float*)d_in[26];
    const float* dec_W3    = (const float*)d_in[27];
    const float* dec_b3    = (const float*)d_in[28];

    float* ws    = (float*)d_ws;
    float* parts = ws + OFF_PART;
    unsigned short* sdec_bf = (unsigned short*)(ws + OFF_SDEC);   // [1024][128]
    unsigned short* Wb      = (unsigned short*)(ws + OFF_WBF);    // Wk|Wv bf16 [256][768]
    unsigned short* Wq_bf   = Wb + 196608;
    unsigned short* Wih_bf  = Wb + 212992;
    unsigned short* Whh_bf  = Wb + 262144;
    unsigned short* W1_bf   = Wb + 311296;
    unsigned short* W2_bf   = Wb + 327680;
    unsigned short* dW1_bf  = Wb + 344064;   // [256][128]
    unsigned short* dW2_bf  = Wb + 376832;   // [768][256]
    unsigned short* dW3_bf  = Wb + 573440;   // [768][768]
    unsigned short* kp_bf   = (unsigned short*)(ws + OFF_KPBF);   // [128][208][128]
    unsigned short* vpT_bf  = (unsigned short*)(ws + OFF_VPTBF);  // [128][128][224]
    unsigned short* Abf     = (unsigned short*)(ws + OFF_ABF);    // [25088][768]
    // decoder intermediates alias the Abf region (dead after mfma_proj_k)
    float*          sf      = ws + OFF_ABF;                        // [1024][768] fp32
    unsigned short* h1_bf   = (unsigned short*)(ws + OFF_ABF + 786432);           // [1024][256]
    unsigned short* h2_bf   = (unsigned short*)(ws + OFF_ABF + 786432 + 131072);  // [1024][768]

    float* out_slots = (float*)d_out;               // [128,8,128]
    float* out_attn  = out_slots + 131072;          // [128,196,8]
    float* out_loss  = out_slots + 331776;          // scalar

    // bf16 weight conversions (2048 elems per block)
    WCArgs wa;
    wa.m[0] = {Wk,     Wb,      0.08838834764831845f, 0};    // 48 blocks
    wa.m[1] = {Wv,     Wb + 98304, 1.f,               48};   // 48
    wa.m[2] = {Wq,     Wq_bf,   1.f,                  96};   // 8
    wa.m[3] = {W_ih,   Wih_bf,  1.f,                  104};  // 24
    wa.m[4] = {W_hh,   Whh_bf,  1.f,                  128};  // 24
    wa.m[5] = {mlp_W1, W1_bf,   1.f,                  152};  // 8
    wa.m[6] = {mlp_W2, W2_bf,   1.f,                  160};  // 8
    wa.m[7] = {dec_W1, dW1_bf,  1.f,                  168};  // 16
    wa.m[8] = {dec_W2, dW2_bf,  1.f,                  184};  // 96
    wa.m[9] = {dec_W3, dW3_bf,  1.f,                  280};  // 288 -> total 568
    wconv_all<<<568, 256, 0, stream>>>(wa);

    padzero_k<<<640, 256, 0, stream>>>(kp_bf, vpT_bf);
    ln_bf16_k<<<BNR / 4, 256, 0, stream>>>(feats, ln_in_g, ln_in_b, Abf);
    mfma_proj_k<<<dim3(BNR / 128, 2), 256, 0, stream>>>(Abf, Wb, kp_bf, vpT_bf);

    slot_iter_mfma<<<B_, 512, 0, stream>>>(noise, ln_slot_g, ln_slot_b, ln_out_g, ln_out_b,
                                           ln_dec_g, ln_dec_b, mu, log_sigma,
                                           Wq_bf, Wih_bf, Whh_bf, b_ih, b_hh,
                                           W1_bf, mlp_b1, W2_bf, mlp_b2, kp_bf, vpT_bf,
                                           out_slots, out_attn, sdec_bf);

    // decoder: 3 bf16 MFMA GEMMs over M=1024
    mfma_mlp_k<128, 0><<<dim3(8, 2), 256, 0, stream>>>(sdec_bf, dW1_bf, dec_b1, h1_bf, nullptr, 256);
    mfma_mlp_k<256, 0><<<dim3(8, 6), 256, 0, stream>>>(h1_bf,  dW2_bf, dec_b2, h2_bf, nullptr, 768);
    mfma_mlp_k<768, 1><<<dim3(8, 6), 256, 0, stream>>>(h2_bf,  dW3_bf, dec_b3, nullptr, sf, 768);

    recon_loss_k<<<dim3(B_, 4), 256, 0, stream>>>(feats, out_attn, sf, parts);
    loss_final_k<<<1, 512, 0, stream>>>(parts, out_loss);
}

// Round 6
// 200.911 us; speedup vs baseline: 2.5374x; 1.0078x over previous
//
#include <hip/hip_runtime.h>
#include <hip/hip_bf16.h>
#include <math.h>

// ---------------- problem constants ----------------
#define B_    128
#define N_    196
#define E_    768
#define K_    8
#define D_    128
#define BNR   (B_*N_)        // 25088 rows
#define ITERS 5

// ws layout (float units)
#define OFF_PART   0          // 512
#define OFF_SDEC   512        // ushort[1024*128] = 65536 floats
#define OFF_WBF    66048      // ushort region: 1146880 ushorts = 573440 floats
#define OFF_KPBF   639488     // ushort[128*208*128] = 1703936 floats
#define OFF_VPTBF  2343424    // ushort[128*128*224] = 1835008 floats
#define OFF_ABF    4178432    // ushort[25088*768] = 9633792 floats (aliased after proj)

typedef __attribute__((ext_vector_type(8))) short bf16x8;
typedef __attribute__((ext_vector_type(4))) float f32x4;

#define MFMA16(a, b, c) __builtin_amdgcn_mfma_f32_16x16x32_bf16(a, b, c, 0, 0, 0)

__device__ __forceinline__ float wave_red_sum64(float v) {
    #pragma unroll
    for (int o = 32; o > 0; o >>= 1) v += __shfl_xor(v, o);
    return v;
}

__device__ __forceinline__ unsigned short f2bf(float v) {
    union { float f; unsigned int u; } c; c.f = v;
    unsigned int u = c.u + 0x7fffu + ((c.u >> 16) & 1u);  // RNE
    return (unsigned short)(u >> 16);
}

__device__ __forceinline__ void gl_lds16(const void* g, void* l) {
    __builtin_amdgcn_global_load_lds(
        (const __attribute__((address_space(1))) unsigned int*)g,
        (__attribute__((address_space(3))) unsigned int*)l, 16, 0, 0);
}

// chunk-XOR swizzled LDS addressing (8-bf16 = 16B chunks; XOR low 3 chunk bits with row&7)
__device__ __forceinline__ int swz128(int row, int j) {
    return row * 128 + ((((j >> 3) ^ (row & 7))) << 3) + (j & 7);
}
__device__ __forceinline__ int swz256(int row, int j) {
    return row * 256 + ((((j >> 3) ^ (row & 7))) << 3) + (j & 7);
}
__device__ __forceinline__ bf16x8 ldA128(const unsigned short* base, int row, int kq, int ks) {
    int ch = (ks * 4 + kq) ^ (row & 7);
    return *(const bf16x8*)(base + row * 128 + ch * 8);
}
__device__ __forceinline__ bf16x8 ldA256(const unsigned short* base, int row, int kq, int ks) {
    int ch = (ks * 4 + kq) ^ (row & 7);
    return *(const bf16x8*)(base + row * 256 + ch * 8);
}
__device__ __forceinline__ bf16x8 ldW128(const unsigned short* W, int row, int ks, int kq) {
    return *(const bf16x8*)(W + (size_t)row * 128 + ks * 32 + kq * 8);
}

// ---------------- K0a: WMt = s * (Wk^T Wq)^T  -> bf16 [128][768] ----------------
// WMt[i][e] = s * sum_o Wk[o][e] * Wq[o][i]; grid.x = e-tile (6), 256 threads.
__global__ __launch_bounds__(256) void wfold_k(const float* __restrict__ Wq,
                                               const float* __restrict__ Wk,
                                               unsigned short* __restrict__ WMt) {
    __shared__ __align__(16) unsigned short Aq[128 * 128];
    __shared__ __align__(16) unsigned short Bk[128 * 128];
    const float s = 0.08838834764831845f;  // 128^-0.5
    int t = threadIdx.x;
    int e0 = blockIdx.x * 128;
    for (int idx = t; idx < 16384; idx += 256) {
        int o = idx >> 7, c = idx & 127;
        Aq[swz128(c, o)] = f2bf(Wq[(size_t)o * 128 + c]);           // Aq[i][o] = Wq[o][i]
        Bk[swz128(c, o)] = f2bf(Wk[(size_t)o * 768 + e0 + c] * s);  // Bk[e][o] = s*Wk[o][e]
    }
    __syncthreads();
    int w = t >> 6, l = t & 63;
    int wr = w >> 1, wc = w & 1, fr = l & 15, kq = l >> 4;
    f32x4 acc[4][4];
    #pragma unroll
    for (int mi = 0; mi < 4; ++mi)
        #pragma unroll
        for (int nj = 0; nj < 4; ++nj) acc[mi][nj] = (f32x4){0.f, 0.f, 0.f, 0.f};
    #pragma unroll
    for (int ks = 0; ks < 4; ++ks) {
        bf16x8 af[4], bfr[4];
        #pragma unroll
        for (int mi = 0; mi < 4; ++mi) af[mi] = ldA128(Aq, wr * 64 + mi * 16 + fr, kq, ks);
        #pragma unroll
        for (int nj = 0; nj < 4; ++nj) bfr[nj] = ldA128(Bk, wc * 64 + nj * 16 + fr, kq, ks);
        #pragma unroll
        for (int mi = 0; mi < 4; ++mi)
            #pragma unroll
            for (int nj = 0; nj < 4; ++nj)
                acc[mi][nj] = MFMA16(af[mi], bfr[nj], acc[mi][nj]);
    }
    #pragma unroll
    for (int mi = 0; mi < 4; ++mi) {
        int rowbase = wr * 64 + mi * 16 + kq * 4;
        #pragma unroll
        for (int nj = 0; nj < 4; ++nj) {
            int col = e0 + wc * 64 + nj * 16 + fr;
            #pragma unroll
            for (int r = 0; r < 4; ++r)
                WMt[(size_t)(rowbase + r) * 768 + col] = f2bf(acc[mi][nj][r]);
        }
    }
}

// ---------------- K0b: weights->bf16 conversions + kp/vpT pad zeroing (merged) ----------------
struct WCEnt { const float* s; unsigned short* d; int t0; };
struct WCArgs { WCEnt m[8]; };

__global__ __launch_bounds__(256) void wprep_k(WCArgs a,
                                               unsigned short* __restrict__ kpb,
                                               unsigned short* __restrict__ vpt) {
    int bid = blockIdx.x;
    if (bid < 512) {  // conversion path
        int i = 0;
        #pragma unroll
        for (int j = 1; j < 8; ++j) if (bid >= a.m[j].t0) i = j;
        int off = (bid - a.m[i].t0) * 2048 + threadIdx.x * 8;
        const float* s = a.m[i].s + off;
        unsigned short* d = a.m[i].d + off;
        float4 v0 = *(const float4*)s, v1 = *(const float4*)(s + 4);
        ushort4 o0, o1;
        o0.x = f2bf(v0.x); o0.y = f2bf(v0.y); o0.z = f2bf(v0.z); o0.w = f2bf(v0.w);
        o1.x = f2bf(v1.x); o1.y = f2bf(v1.y); o1.z = f2bf(v1.z); o1.w = f2bf(v1.w);
        *(ushort4*)d = o0; *(ushort4*)(d + 4) = o1;
    } else {          // pad-zero path
        int i = (bid - 512) * 256 + threadIdx.x;   // ushort4 index, 163840 total
        ushort4 z = {0, 0, 0, 0};
        if (i < 49152) {                 // kp pads: 128 b x 12 rows x 128
            int q = i * 4;
            int b = q / 1536, off = q - b * 1536;
            *(ushort4*)(kpb + ((size_t)b * 208 + 196) * 128 + off) = z;
        } else {                          // vpT pads: per (b,d) cols 196..223
            int c = i - 49152;            // 0..114687
            int bd = c / 7, cc = c - bd * 7;
            *(ushort4*)(vpt + (size_t)bd * 224 + 196 + cc * 4) = z;
        }
    }
}

// ---------------- K1: one-pass LayerNorm(features) -> bf16 ----------------
__global__ __launch_bounds__(256) void ln_bf16_k(const float* __restrict__ f,
                                                 const float* __restrict__ g,
                                                 const float* __restrict__ bv,
                                                 unsigned short* __restrict__ out) {
    int wid = blockIdx.x * 4 + (threadIdx.x >> 6);   // one wave per row
    int lane = threadIdx.x & 63;
    const float* row = f + (size_t)wid * E_;
    float4 x[3];
    float s = 0.f, s2 = 0.f;
    #pragma unroll
    for (int c = 0; c < 3; ++c) {
        x[c] = *(const float4*)(row + c * 256 + lane * 4);
        s  += x[c].x + x[c].y + x[c].z + x[c].w;
        s2 += x[c].x * x[c].x + x[c].y * x[c].y + x[c].z * x[c].z + x[c].w * x[c].w;
    }
    s  = wave_red_sum64(s);
    s2 = wave_red_sum64(s2);
    float m = s * (1.f / E_);
    float rs = rsqrtf(s2 * (1.f / E_) - m * m + 1e-5f);
    #pragma unroll
    for (int c = 0; c < 3; ++c) {
        float4 g4 = *(const float4*)(g + c * 256 + lane * 4);
        float4 b4 = *(const float4*)(bv + c * 256 + lane * 4);
        ushort4 o;
        o.x = f2bf((x[c].x - m) * rs * g4.x + b4.x);
        o.y = f2bf((x[c].y - m) * rs * g4.y + b4.y);
        o.z = f2bf((x[c].z - m) * rs * g4.z + b4.z);
        o.w = f2bf((x[c].w - m) * rs * g4.w + b4.w);
        *(ushort4*)(out + (size_t)wid * E_ + c * 256 + lane * 4) = o;
    }
}

// ---------------- K2: bf16 MFMA GEMM -> kpq_bf (y=0) / vpT_bf (y=1) ----------------
__global__ __launch_bounds__(256) void mfma_proj_k(const unsigned short* __restrict__ Abf,
                                                   const unsigned short* __restrict__ WMt,
                                                   const unsigned short* __restrict__ Wv_bf,
                                                   unsigned short* __restrict__ kpq_bf,
                                                   unsigned short* __restrict__ vpT_bf) {
    __shared__ __align__(16) unsigned short As[128 * 64];
    __shared__ __align__(16) unsigned short Bs[128 * 64];
    const int t = threadIdx.x, w = t >> 6, l = t & 63;
    const int m0 = blockIdx.x * 128;
    const unsigned short* Wbase = (blockIdx.y == 0) ? WMt : Wv_bf;
    const int wr = w >> 1, wc = w & 1;
    const int fr = l & 15, kq = l >> 4;
    f32x4 acc[4][4];
    #pragma unroll
    for (int mi = 0; mi < 4; ++mi)
        #pragma unroll
        for (int nj = 0; nj < 4; ++nj) acc[mi][nj] = (f32x4){0.f, 0.f, 0.f, 0.f};

    for (int ks = 0; ks < E_; ks += 64) {
        __syncthreads();
        #pragma unroll
        for (int j = 0; j < 4; ++j) {
            int ci = (w << 8) + (j << 6) + l;
            int r = ci >> 3, c = ci & 7;
            int cg = c ^ (r & 7);
            gl_lds16(Abf   + (size_t)(m0 + r) * E_ + ks + cg * 8,
                     As + (size_t)((w << 8) + (j << 6)) * 8);
            gl_lds16(Wbase + (size_t)r * E_ + ks + cg * 8,
                     Bs + (size_t)((w << 8) + (j << 6)) * 8);
        }
        __syncthreads();
        #pragma unroll
        for (int kk = 0; kk < 2; ++kk) {
            bf16x8 af[4], bfr[4];
            int ch = (kk * 4 + kq) ^ (fr & 7);
            #pragma unroll
            for (int mi = 0; mi < 4; ++mi)
                af[mi] = *(const bf16x8*)(As + (wr * 64 + mi * 16 + fr) * 64 + ch * 8);
            #pragma unroll
            for (int nj = 0; nj < 4; ++nj)
                bfr[nj] = *(const bf16x8*)(Bs + (wc * 64 + nj * 16 + fr) * 64 + ch * 8);
            #pragma unroll
            for (int mi = 0; mi < 4; ++mi)
                #pragma unroll
                for (int nj = 0; nj < 4; ++nj)
                    acc[mi][nj] = MFMA16(af[mi], bfr[nj], acc[mi][nj]);
        }
    }
    if (blockIdx.y == 0) {
        #pragma unroll
        for (int mi = 0; mi < 4; ++mi) {
            int rowbase = m0 + wr * 64 + mi * 16 + kq * 4;
            #pragma unroll
            for (int r = 0; r < 4; ++r) {
                int m = rowbase + r;
                int b = m / 196, rr = m - b * 196;
                size_t o = ((size_t)b * 208 + rr) * 128;
                #pragma unroll
                for (int nj = 0; nj < 4; ++nj)
                    kpq_bf[o + wc * 64 + nj * 16 + fr] = f2bf(acc[mi][nj][r]);
            }
        }
    } else {
        #pragma unroll
        for (int mi = 0; mi < 4; ++mi) {
            int rowbase = m0 + wr * 64 + mi * 16 + kq * 4;
            #pragma unroll
            for (int r = 0; r < 4; ++r) {
                int m = rowbase + r;
                int b = m / 196, rr = m - b * 196;
                #pragma unroll
                for (int nj = 0; nj < 4; ++nj) {
                    int col = wc * 64 + nj * 16 + fr;
                    vpT_bf[((size_t)b * 128 + col) * 224 + rr] = f2bf(acc[mi][nj][r]);
                }
            }
        }
    }
}

// ---------------- K2b: generic MLP-layer MFMA GEMM ----------------
template<int KTOT, int EPI>
__global__ __launch_bounds__(256) void mfma_mlp_k(const unsigned short* __restrict__ A,
                                                  const unsigned short* __restrict__ Bw,
                                                  const float* __restrict__ bias,
                                                  unsigned short* __restrict__ out_bf,
                                                  float* __restrict__ out_f,
                                                  int ldN) {
    __shared__ __align__(16) unsigned short As[128 * 64];
    __shared__ __align__(16) unsigned short Bs[128 * 64];
    const int t = threadIdx.x, w = t >> 6, l = t & 63;
    const int m0 = blockIdx.x * 128;
    const int n0 = blockIdx.y * 128;
    const int wr = w >> 1, wc = w & 1;
    const int fr = l & 15, kq = l >> 4;
    f32x4 acc[4][4];
    #pragma unroll
    for (int mi = 0; mi < 4; ++mi)
        #pragma unroll
        for (int nj = 0; nj < 4; ++nj) acc[mi][nj] = (f32x4){0.f, 0.f, 0.f, 0.f};

    for (int ks = 0; ks < KTOT; ks += 64) {
        __syncthreads();
        #pragma unroll
        for (int j = 0; j < 4; ++j) {
            int ci = (w << 8) + (j << 6) + l;
            int r = ci >> 3, c = ci & 7;
            int cg = c ^ (r & 7);
            gl_lds16(A  + (size_t)(m0 + r) * KTOT + ks + cg * 8,
                     As + (size_t)((w << 8) + (j << 6)) * 8);
            gl_lds16(Bw + (size_t)(n0 + r) * KTOT + ks + cg * 8,
                     Bs + (size_t)((w << 8) + (j << 6)) * 8);
        }
        __syncthreads();
        #pragma unroll
        for (int kk = 0; kk < 2; ++kk) {
            bf16x8 af[4], bfr[4];
            int ch = (kk * 4 + kq) ^ (fr & 7);
            #pragma unroll
            for (int mi = 0; mi < 4; ++mi)
                af[mi] = *(const bf16x8*)(As + (wr * 64 + mi * 16 + fr) * 64 + ch * 8);
            #pragma unroll
            for (int nj = 0; nj < 4; ++nj)
                bfr[nj] = *(const bf16x8*)(Bs + (wc * 64 + nj * 16 + fr) * 64 + ch * 8);
            #pragma unroll
            for (int mi = 0; mi < 4; ++mi)
                #pragma unroll
                for (int nj = 0; nj < 4; ++nj)
                    acc[mi][nj] = MFMA16(af[mi], bfr[nj], acc[mi][nj]);
        }
    }
    #pragma unroll
    for (int mi = 0; mi < 4; ++mi) {
        int rowbase = m0 + wr * 64 + mi * 16 + kq * 4;
        #pragma unroll
        for (int nj = 0; nj < 4; ++nj) {
            int col = n0 + wc * 64 + nj * 16 + fr;
            float bc = bias[col];
            #pragma unroll
            for (int r = 0; r < 4; ++r) {
                float v = acc[mi][nj][r] + bc;
                if (EPI == 0)
                    out_bf[(size_t)(rowbase + r) * ldN + col] = f2bf(fmaxf(v, 0.f));
                else
                    out_f[(size_t)(rowbase + r) * ldN + col] = v;
            }
        }
    }
}

// ---------------- K3: persistent per-batch slot-attention iterations (MFMA) ----------------
// 8 barriers/iter: q folded into kpq (no q phase), colsum fused into softmax,
// GRU mid-barrier removed (gates no longer write slots_bf).
__global__ __launch_bounds__(512) void slot_iter_mfma(
    const float* __restrict__ noise,
    const float* __restrict__ lsg, const float* __restrict__ lsb,
    const float* __restrict__ log_, const float* __restrict__ lob,
    const float* __restrict__ ldg_, const float* __restrict__ ldb_,
    const float* __restrict__ mup, const float* __restrict__ lsig,
    const unsigned short* __restrict__ Wih_bf,
    const unsigned short* __restrict__ Whh_bf,
    const float* __restrict__ bih, const float* __restrict__ bhh,
    const unsigned short* __restrict__ W1_bf, const float* __restrict__ mb1,
    const unsigned short* __restrict__ W2_bf, const float* __restrict__ mb2,
    const unsigned short* __restrict__ kpq_bf,
    const unsigned short* __restrict__ vpT_bf,
    float* __restrict__ out_slots, float* __restrict__ out_attn,
    unsigned short* __restrict__ sdec_bf) {

    __shared__ float slots[8][128];
    __shared__ float attn[208][9];
    __shared__ float colpart[8][8];
    __shared__ __align__(16) unsigned short sln_bf[2048];
    __shared__ __align__(16) unsigned short upd_bf[2048];
    __shared__ __align__(16) unsigned short slots_bf[2048];
    __shared__ __align__(16) unsigned short h_bf[2048];
    __shared__ __align__(16) unsigned short attnT_bf[4096];

    const int b = blockIdx.x, t = threadIdx.x;
    const int lane = t & 63, w = t >> 6;
    const int fr = lane & 15, kq = lane >> 4;

    for (int i = t; i < 2048; i += 512) {
        sln_bf[i] = 0; upd_bf[i] = 0; slots_bf[i] = 0; h_bf[i] = 0;
    }
    for (int i = t; i < 4096; i += 512) attnT_bf[i] = 0;

    for (int idx = t; idx < 1024; idx += 512) {
        int k = idx >> 7, d = idx & 127;
        float v = noise[(size_t)b * 1024 + idx] * expf(lsig[d]) + mup[d];
        slots[k][d] = v;
        slots_bf[swz128(k, d)] = f2bf(v);
    }
    __syncthreads();

    for (int it = 0; it < ITERS; ++it) {
        bool last = (it == ITERS - 1);
        // (a) LN_slot -> sln_bf (wave w owns slot w)
        {
            float x0 = slots[w][lane], x1 = slots[w][lane + 64];
            float s  = wave_red_sum64(x0 + x1);
            float s2 = wave_red_sum64(x0 * x0 + x1 * x1);
            float m = s * 0.0078125f;
            float rs = rsqrtf(s2 * 0.0078125f - m * m + 1e-5f);
            sln_bf[swz128(w, lane)]      = f2bf((x0 - m) * rs * lsg[lane]      + lsb[lane]);
            sln_bf[swz128(w, lane + 64)] = f2bf((x1 - m) * rs * lsg[lane + 64] + lsb[lane + 64]);
        }
        __syncthreads();
        // (c) logits = kpq @ sln^T, softmax over slots, in-register colsum partials
        {
            float cp = 0.f;
            #pragma unroll
            for (int p = 0; p < 2; ++p) {
                int tt = w + p * 8;
                if (tt <= 12) {
                    f32x4 acc = {0.f, 0.f, 0.f, 0.f};
                    const unsigned short* kpr = kpq_bf + ((size_t)b * 208 + tt * 16 + fr) * 128;
                    #pragma unroll
                    for (int ks = 0; ks < 4; ++ks)
                        acc = MFMA16(*(const bf16x8*)(kpr + ks * 32 + kq * 8),
                                     ldA128(sln_bf, fr, kq, ks), acc);
                    #pragma unroll
                    for (int r = 0; r < 4; ++r) {
                        float v = acc[r];
                        float mx = fmaxf(v, __shfl_xor(v, 1));
                        mx = fmaxf(mx, __shfl_xor(mx, 2));
                        mx = fmaxf(mx, __shfl_xor(mx, 4));
                        float e = expf(v - mx);
                        float sm = e;
                        sm += __shfl_xor(sm, 1); sm += __shfl_xor(sm, 2); sm += __shfl_xor(sm, 4);
                        float a = e / sm;
                        int tok = tt * 16 + kq * 4 + r;
                        bool valid = (tok < 196);
                        if (fr < 8 && valid) attn[tok][fr] = a;
                        cp += valid ? a : 0.f;
                    }
                }
            }
            cp += __shfl_xor(cp, 16);
            cp += __shfl_xor(cp, 32);
            if (lane < 8) colpart[w][lane] = cp;   // lane<8 => fr=lane, kq=0
        }
        __syncthreads();
        // (e) normalize over tokens -> attnT_bf (+ out_attn last iter)
        {
            int k = t & 7;    // constant per thread (stride 512 preserves idx&7)
            float cs = colpart[0][k] + colpart[1][k] + colpart[2][k] + colpart[3][k]
                     + colpart[4][k] + colpart[5][k] + colpart[6][k] + colpart[7][k]
                     + 196.0f * 1e-8f;
            float inv = 1.f / cs;
            for (int idx = t; idx < 1568; idx += 512) {
                int n = idx >> 3;
                float raw = attn[n][k];
                attnT_bf[swz256(k, n)] = f2bf((raw + 1e-8f) * inv);
                if (last) out_attn[((size_t)b * 196 + n) * 8 + k] = raw;
            }
        }
        __syncthreads();
        // (f) updates = attn_norm^T @ v -> upd_bf
        {
            f32x4 acc = {0.f, 0.f, 0.f, 0.f};
            const unsigned short* vpr = vpT_bf + ((size_t)b * 128 + w * 16 + fr) * 224;
            #pragma unroll
            for (int ks = 0; ks < 7; ++ks)
                acc = MFMA16(ldA256(attnT_bf, fr, kq, ks),
                             *(const bf16x8*)(vpr + ks * 32 + kq * 8), acc);
            if (kq < 2) {
                #pragma unroll
                for (int r = 0; r < 4; ++r)
                    upd_bf[swz128(kq * 4 + r, w * 16 + fr)] = f2bf(acc[r]);
            }
        }
        __syncthreads();
        // (g) GRU: 24 MFMAs + gates (single barrier; gates don't touch slots_bf)
        {
            f32x4 gi0 = {0,0,0,0}, gi1 = {0,0,0,0}, gi2 = {0,0,0,0};
            f32x4 gh0 = {0,0,0,0}, gh1 = {0,0,0,0}, gh2 = {0,0,0,0};
            #pragma unroll
            for (int ks = 0; ks < 4; ++ks) {
                bf16x8 au = ldA128(upd_bf,   fr, kq, ks);
                bf16x8 as = ldA128(slots_bf, fr, kq, ks);
                gi0 = MFMA16(au, ldW128(Wih_bf,       w * 16 + fr, ks, kq), gi0);
                gi1 = MFMA16(au, ldW128(Wih_bf, 128 + w * 16 + fr, ks, kq), gi1);
                gi2 = MFMA16(au, ldW128(Wih_bf, 256 + w * 16 + fr, ks, kq), gi2);
                gh0 = MFMA16(as, ldW128(Whh_bf,       w * 16 + fr, ks, kq), gh0);
                gh1 = MFMA16(as, ldW128(Whh_bf, 128 + w * 16 + fr, ks, kq), gh1);
                gh2 = MFMA16(as, ldW128(Whh_bf, 256 + w * 16 + fr, ks, kq), gh2);
            }
            if (kq < 2) {
                int d = w * 16 + fr;
                float bi0 = bih[d], bi1 = bih[128 + d], bi2 = bih[256 + d];
                float bh0 = bhh[d], bh1 = bhh[128 + d], bh2 = bhh[256 + d];
                #pragma unroll
                for (int r = 0; r < 4; ++r) {
                    int m = kq * 4 + r;
                    float rr = 1.f / (1.f + expf(-((gi0[r] + bi0) + (gh0[r] + bh0))));
                    float zz = 1.f / (1.f + expf(-((gi1[r] + bi1) + (gh1[r] + bh1))));
                    float nn = tanhf((gi2[r] + bi2) + rr * (gh2[r] + bh2));
                    float h = slots[m][d];
                    slots[m][d] = (1.f - zz) * nn + zz * h;
                }
            }
        }
        __syncthreads();
        // (h) LN_out -> sln_bf
        {
            float x0 = slots[w][lane], x1 = slots[w][lane + 64];
            float s  = wave_red_sum64(x0 + x1);
            float s2 = wave_red_sum64(x0 * x0 + x1 * x1);
            float m = s * 0.0078125f;
            float rs = rsqrtf(s2 * 0.0078125f - m * m + 1e-5f);
            sln_bf[swz128(w, lane)]      = f2bf((x0 - m) * rs * log_[lane]      + lob[lane]);
            sln_bf[swz128(w, lane + 64)] = f2bf((x1 - m) * rs * log_[lane + 64] + lob[lane + 64]);
        }
        __syncthreads();
        // (i) MLP1 -> h_bf
        {
            f32x4 acc = {0.f, 0.f, 0.f, 0.f};
            #pragma unroll
            for (int ks = 0; ks < 4; ++ks)
                acc = MFMA16(ldA128(sln_bf, fr, kq, ks), ldW128(W1_bf, w * 16 + fr, ks, kq), acc);
            if (kq < 2) {
                float b1 = mb1[w * 16 + fr];
                #pragma unroll
                for (int r = 0; r < 4; ++r)
                    h_bf[swz128(kq * 4 + r, w * 16 + fr)] = f2bf(fmaxf(acc[r] + b1, 0.f));
            }
        }
        __syncthreads();
        // (j) MLP2 residual -> slots, slots_bf (GRU h for next iter)
        {
            f32x4 acc = {0.f, 0.f, 0.f, 0.f};
            #pragma unroll
            for (int ks = 0; ks < 4; ++ks)
                acc = MFMA16(ldA128(h_bf, fr, kq, ks), ldW128(W2_bf, w * 16 + fr, ks, kq), acc);
            if (kq < 2) {
                float b2 = mb2[w * 16 + fr];
                #pragma unroll
                for (int r = 0; r < 4; ++r) {
                    int m = kq * 4 + r, d = w * 16 + fr;
                    float v = slots[m][d] + acc[r] + b2;
                    slots[m][d] = v;
                    slots_bf[swz128(m, d)] = f2bf(v);
                }
            }
        }
        __syncthreads();
    }
    // epilogue: raw slots out + fused LN_dec -> sdec_bf
    {
        float x0 = slots[w][lane], x1 = slots[w][lane + 64];
        out_slots[(size_t)b * 1024 + w * 128 + lane]      = x0;
        out_slots[(size_t)b * 1024 + w * 128 + lane + 64] = x1;
        float s  = wave_red_sum64(x0 + x1);
        float s2 = wave_red_sum64(x0 * x0 + x1 * x1);
        float m = s * 0.0078125f;
        float rs = rsqrtf(s2 * 0.0078125f - m * m + 1e-5f);
        sdec_bf[((size_t)b * 8 + w) * 128 + lane]      = f2bf((x0 - m) * rs * ldg_[lane]      + ldb_[lane]);
        sdec_bf[((size_t)b * 8 + w) * 128 + lane + 64] = f2bf((x1 - m) * rs * ldg_[lane + 64] + ldb_[lane + 64]);
    }
}

// ---------------- K5: fused recon + squared-error partial sums ----------------
__global__ __launch_bounds__(256) void recon_loss_k(
    const float* __restrict__ feats, const float* __restrict__ attnv,
    const float* __restrict__ sf, float* __restrict__ partials) {

    __shared__ float sfl[8][768];
    __shared__ float al[49][8];
    __shared__ float wred[4];
    int b = blockIdx.x, qd = blockIdx.y, t = threadIdx.x;
    for (int idx = t; idx < 8 * 768; idx += 256)
        ((float*)sfl)[idx] = sf[(size_t)b * 8 * 768 + idx];
    int n0 = qd * 49;
    for (int idx = t; idx < 49 * 8; idx += 256)
        ((float*)al)[idx] = attnv[((size_t)b * N_ + n0) * 8 + idx];
    __syncthreads();
    float acc = 0.f;
    for (int nl = 0; nl < 49; ++nl) {
        float a0 = al[nl][0], a1 = al[nl][1], a2 = al[nl][2], a3 = al[nl][3];
        float a4 = al[nl][4], a5 = al[nl][5], a6 = al[nl][6], a7 = al[nl][7];
        const float* frow = feats + ((size_t)(b * N_ + n0 + nl)) * E_;
        for (int c = t; c < E_; c += 256) {
            float r = sfl[0][c]*a0 + sfl[1][c]*a1 + sfl[2][c]*a2 + sfl[3][c]*a3
                    + sfl[4][c]*a4 + sfl[5][c]*a5 + sfl[6][c]*a6 + sfl[7][c]*a7;
            float d = r - frow[c];
            acc += d * d;
        }
    }
    acc = wave_red_sum64(acc);
    int lane = t & 63, w = t >> 6;
    if (lane == 0) wred[w] = acc;
    __syncthreads();
    if (t == 0) partials[b * 4 + qd] = wred[0] + wred[1] + wred[2] + wred[3];
}

__global__ __launch_bounds__(512) void loss_final_k(const float* __restrict__ partials,
                                                    float* __restrict__ out) {
    __shared__ float wred[8];
    int t = threadIdx.x;
    float v = partials[t];
    v = wave_red_sum64(v);
    if ((t & 63) == 0) wred[t >> 6] = v;
    __syncthreads();
    if (t == 0) {
        float s = 0.f;
        #pragma unroll
        for (int i = 0; i < 8; ++i) s += wred[i];
        out[0] = s / (float)(B_ * N_ * E_);
    }
}

// ---------------- launch ----------------
extern "C" void kernel_launch(void* const* d_in, const int* in_sizes, int n_in,
                              void* d_out, int out_size, void* d_ws, size_t ws_size,
                              hipStream_t stream) {
    (void)in_sizes; (void)n_in; (void)out_size; (void)ws_size;
    const float* feats     = (const float*)d_in[0];
    const float* noise     = (const float*)d_in[1];
    const float* ln_in_g   = (const float*)d_in[2];
    const float* ln_in_b   = (const float*)d_in[3];
    const float* ln_slot_g = (const float*)d_in[4];
    const float* ln_slot_b = (const float*)d_in[5];
    const float* ln_out_g  = (const float*)d_in[6];
    const float* ln_out_b  = (const float*)d_in[7];
    const float* ln_dec_g  = (const float*)d_in[8];
    const float* ln_dec_b  = (const float*)d_in[9];
    const float* mu        = (const float*)d_in[10];
    const float* log_sigma = (const float*)d_in[11];
    const float* Wk        = (const float*)d_in[12];
    const float* Wq        = (const float*)d_in[13];
    const float* Wv        = (const float*)d_in[14];
    const float* W_ih      = (const float*)d_in[15];
    const float* W_hh      = (const float*)d_in[16];
    const float* b_ih      = (const float*)d_in[17];
    const float* b_hh      = (const float*)d_in[18];
    const float* mlp_W1    = (const float*)d_in[19];
    const float* mlp_b1    = (const float*)d_in[20];
    const float* mlp_W2    = (const float*)d_in[21];
    const float* mlp_b2    = (const float*)d_in[22];
    const float* dec_W1    = (const float*)d_in[23];
    const float* dec_b1    = (const float*)d_in[24];
    const float* dec_W2    = (const float*)d_in[25];
    const float* dec_b2    = (const float*)d_in[26];
    const float* dec_W3    = (const float*)d_in[27];
    const float* dec_b3    = (const float*)d_in[28];

    float* ws    = (float*)d_ws;
    float* parts = ws + OFF_PART;
    unsigned short* sdec_bf = (unsigned short*)(ws + OFF_SDEC);   // [1024][128]
    unsigned short* Wbase   = (unsigned short*)(ws + OFF_WBF);
    unsigned short* Wv_bf   = Wbase;              // [128][768]
    unsigned short* Wih_bf  = Wbase + 98304;      // [384][128]
    unsigned short* Whh_bf  = Wbase + 147456;     // [384][128]
    unsigned short* W1_bf   = Wbase + 196608;     // [128][128]
    unsigned short* W2_bf   = Wbase + 212992;     // [128][128]
    unsigned short* dW1_bf  = Wbase + 229376;     // [256][128]
    unsigned short* dW2_bf  = Wbase + 262144;     // [768][256]
    unsigned short* dW3_bf  = Wbase + 458752;     // [768][768]
    unsigned short* WMt     = Wbase + 1048576;    // [128][768]
    unsigned short* kpq_bf  = (unsigned short*)(ws + OFF_KPBF);   // [128][208][128]
    unsigned short* vpT_bf  = (unsigned short*)(ws + OFF_VPTBF);  // [128][128][224]
    unsigned short* Abf     = (unsigned short*)(ws + OFF_ABF);    // [25088][768]
    // decoder intermediates alias the Abf region (dead after mfma_proj_k)
    float*          sf      = ws + OFF_ABF;                        // [1024][768] fp32
    unsigned short* h1_bf   = (unsigned short*)(ws + OFF_ABF + 786432);           // [1024][256]
    unsigned short* h2_bf   = (unsigned short*)(ws + OFF_ABF + 786432 + 131072);  // [1024][768]

    float* out_slots = (float*)d_out;               // [128,8,128]
    float* out_attn  = out_slots + 131072;          // [128,196,8]
    float* out_loss  = out_slots + 331776;          // scalar

    // WMt = s*(Wk^T Wq)^T (reads raw fp32 Wq/Wk)
    wfold_k<<<6, 256, 0, stream>>>(Wq, Wk, WMt);

    // weights->bf16 + pad zeroing, one launch (512 conv blocks + 640 pad blocks)
    WCArgs wa;
    wa.m[0] = {Wv,     Wv_bf,  0};     // 48 blocks
    wa.m[1] = {W_ih,   Wih_bf, 48};    // 24
    wa.m[2] = {W_hh,   Whh_bf, 72};    // 24
    wa.m[3] = {mlp_W1, W1_bf,  96};    // 8
    wa.m[4] = {mlp_W2, W2_bf,  104};   // 8
    wa.m[5] = {dec_W1, dW1_bf, 112};   // 16
    wa.m[6] = {dec_W2, dW2_bf, 128};   // 96
    wa.m[7] = {dec_W3, dW3_bf, 224};   // 288 -> 512 total conv
    wprep_k<<<1152, 256, 0, stream>>>(wa, kpq_bf, vpT_bf);

    ln_bf16_k<<<BNR / 4, 256, 0, stream>>>(feats, ln_in_g, ln_in_b, Abf);
    mfma_proj_k<<<dim3(BNR / 128, 2), 256, 0, stream>>>(Abf, WMt, Wv_bf, kpq_bf, vpT_bf);

    slot_iter_mfma<<<B_, 512, 0, stream>>>(noise, ln_slot_g, ln_slot_b, ln_out_g, ln_out_b,
                                           ln_dec_g, ln_dec_b, mu, log_sigma,
                                           Wih_bf, Whh_bf, b_ih, b_hh,
                                           W1_bf, mlp_b1, W2_bf, mlp_b2, kpq_bf, vpT_bf,
                                           out_slots, out_attn, sdec_bf);

    // decoder: 3 bf16 MFMA GEMMs over M=1024
    mfma_mlp_k<128, 0><<<dim3(8, 2), 256, 0, stream>>>(sdec_bf, dW1_bf, dec_b1, h1_bf, nullptr, 256);
    mfma_mlp_k<256, 0><<<dim3(8, 6), 256, 0, stream>>>(h1_bf,  dW2_bf, dec_b2, h2_bf, nullptr, 768);
    mfma_mlp_k<768, 1><<<dim3(8, 6), 256, 0, stream>>>(h2_bf,  dW3_bf, dec_b3, nullptr, sf, 768);

    recon_loss_k<<<dim3(B_, 4), 256, 0, stream>>>(feats, out_attn, sf, parts);
    loss_final_k<<<1, 512, 0, stream>>>(parts, out_loss);
}